// Round 1
// baseline (1849.037 us; speedup 1.0000x reference)
//
#include <hip/hip_runtime.h>
#include <hip/hip_bf16.h>

// GraphSAGE 2-layer + link predictor.
// Pipeline: detect idx dtype -> memset ws -> scatter1(deg,agg1) -> update1(h1)
//           -> scatter2(agg2) -> update2(h2) -> linkpred(out)

__device__ __forceinline__ long load_idx(const void* p, long i, int is64) {
    if (is64) return (long)((const long long*)p)[i];
    return (long)((const int*)p)[i];
}

// Decide whether index arrays are int64 (odd dwords all zero) or int32.
__global__ void detect64_kernel(const void* eidx, int* flag) {
    const unsigned* u = (const unsigned*)eidx;
    unsigned acc = 0;
    for (int i = 0; i < 64; ++i) acc |= u[2 * i + 1];
    *flag = (acc == 0u) ? 1 : 0;
}

// One edge per 64-thread group; lane f handles feature f. Also counts degree.
__global__ void scatter1_kernel(const void* eidx, const int* flag,
                                const float* __restrict__ x,
                                float* __restrict__ agg1,
                                float* __restrict__ deg, long E) {
    long gid = (long)blockIdx.x * 256 + threadIdx.x;
    long e = gid >> 6;
    int f = (int)(gid & 63);
    if (e >= E) return;
    int is64 = *flag;
    long src = load_idx(eidx, e, is64);
    long dst = load_idx(eidx, E + e, is64);
    atomicAdd(&agg1[dst * 64 + f], x[src * 64 + f]);
    if (f == 0) atomicAdd(&deg[dst], 1.0f);
}

// One edge per 128-thread group over h1 (128 features).
__global__ void scatter2_kernel(const void* eidx, const int* flag,
                                const float* __restrict__ h1,
                                float* __restrict__ agg2, long E) {
    long gid = (long)blockIdx.x * 256 + threadIdx.x;
    long e = gid >> 7;
    int f = (int)(gid & 127);
    if (e >= E) return;
    int is64 = *flag;
    long src = load_idx(eidx, e, is64);
    long dst = load_idx(eidx, E + e, is64);
    atomicAdd(&agg2[dst * 128 + f], h1[src * 128 + f]);
}

#define NPB 16  // nodes per block in update kernels

// h1[n][o] = relu( sum_k W1l[o][k]*agg1n[n][k] + W1r[o][k]*x[n][k] + b1[o] )
__global__ void update1_kernel(const float* __restrict__ x,
                               const float* __restrict__ agg1,
                               const float* __restrict__ deg,
                               const float* __restrict__ W1l,
                               const float* __restrict__ W1r,
                               const float* __restrict__ b1,
                               float* __restrict__ h1, long N) {
    __shared__ float wl[64][129];   // [k][o], padded
    __shared__ float wr[64][129];
    __shared__ float xs[NPB][64];
    __shared__ float as[NPB][64];
    __shared__ float bs[128];
    int tid = threadIdx.x;
    for (int idx = tid; idx < 128 * 64; idx += 256) {
        int o = idx >> 6, k = idx & 63;
        wl[k][o] = W1l[idx];
        wr[k][o] = W1r[idx];
    }
    if (tid < 128) bs[tid] = b1[tid];
    long node0 = (long)blockIdx.x * NPB;
    for (int idx = tid; idx < NPB * 64; idx += 256) {
        int nl = idx >> 6, k = idx & 63;
        long n = node0 + nl;
        float xv = 0.f, av = 0.f;
        if (n < N) {
            xv = x[n * 64 + k];
            av = agg1[n * 64 + k] / fmaxf(deg[n], 1.0f);
        }
        xs[nl][k] = xv;
        as[nl][k] = av;
    }
    __syncthreads();
    int o = tid & 127;
    int half = tid >> 7;
    for (int i = 0; i < NPB / 2; ++i) {
        int nl = half + 2 * i;
        long n = node0 + nl;
        if (n >= N) continue;
        float acc = bs[o];
#pragma unroll
        for (int k = 0; k < 64; ++k)
            acc += wl[k][o] * as[nl][k] + wr[k][o] * xs[nl][k];
        h1[n * 128 + o] = fmaxf(acc, 0.f);
    }
}

// h2[n][o] = sum_k W2l[o][k]*agg2n[n][k] + W2r[o][k]*h1[n][k] + b2[o]
__global__ void update2_kernel(const float* __restrict__ h1,
                               const float* __restrict__ agg2,
                               const float* __restrict__ deg,
                               const float* __restrict__ W2l,
                               const float* __restrict__ W2r,
                               const float* __restrict__ b2,
                               float* __restrict__ h2, long N) {
    __shared__ float wl[128][65];   // [k][o], padded
    __shared__ float wr[128][65];
    __shared__ float hs[NPB][128];
    __shared__ float as[NPB][128];
    __shared__ float bs[64];
    int tid = threadIdx.x;
    for (int idx = tid; idx < 64 * 128; idx += 256) {
        int o = idx >> 7, k = idx & 127;
        wl[k][o] = W2l[idx];
        wr[k][o] = W2r[idx];
    }
    if (tid < 64) bs[tid] = b2[tid];
    long node0 = (long)blockIdx.x * NPB;
    for (int idx = tid; idx < NPB * 128; idx += 256) {
        int nl = idx >> 7, k = idx & 127;
        long n = node0 + nl;
        float hv = 0.f, av = 0.f;
        if (n < N) {
            hv = h1[n * 128 + k];
            av = agg2[n * 128 + k] / fmaxf(deg[n], 1.0f);
        }
        hs[nl][k] = hv;
        as[nl][k] = av;
    }
    __syncthreads();
    int o = tid & 63;
    int q = tid >> 6;
    for (int i = 0; i < NPB / 4; ++i) {
        int nl = q + 4 * i;
        long n = node0 + nl;
        if (n >= N) continue;
        float acc = bs[o];
#pragma unroll
        for (int k = 0; k < 128; ++k)
            acc += wl[k][o] * as[nl][k] + wr[k][o] * hs[nl][k];
        h2[n * 64 + o] = acc;
    }
}

__global__ void linkpred_kernel(const void* pairs, const int* flag,
                                const float* __restrict__ h2,
                                const float* __restrict__ Wlp,
                                const float* __restrict__ blp,
                                float* __restrict__ out, long P) {
    __shared__ float w[128];
    __shared__ float bb;
    int tid = threadIdx.x;
    if (tid < 128) w[tid] = Wlp[tid];
    if (tid == 0) bb = blp[0];
    __syncthreads();
    long p = (long)blockIdx.x * 256 + tid;
    if (p >= P) return;
    int is64 = *flag;
    long s = load_idx(pairs, 2 * p, is64);
    long d = load_idx(pairs, 2 * p + 1, is64);
    float acc = bb;
    const float4* hs = (const float4*)(h2 + s * 64);
    const float4* hd = (const float4*)(h2 + d * 64);
#pragma unroll
    for (int j = 0; j < 16; ++j) {
        float4 v = hs[j];
        acc += v.x * w[j * 4] + v.y * w[j * 4 + 1] + v.z * w[j * 4 + 2] + v.w * w[j * 4 + 3];
    }
#pragma unroll
    for (int j = 0; j < 16; ++j) {
        float4 v = hd[j];
        acc += v.x * w[64 + j * 4] + v.y * w[64 + j * 4 + 1] + v.z * w[64 + j * 4 + 2] + v.w * w[64 + j * 4 + 3];
    }
    out[p] = 1.0f / (1.0f + expf(-acc));
}

extern "C" void kernel_launch(void* const* d_in, const int* in_sizes, int n_in,
                              void* d_out, int out_size, void* d_ws, size_t ws_size,
                              hipStream_t stream) {
    const float* x   = (const float*)d_in[0];
    const void*  eidx = d_in[1];
    const void*  pairs = d_in[2];
    const float* W1l = (const float*)d_in[3];
    const float* W1r = (const float*)d_in[4];
    const float* b1  = (const float*)d_in[5];
    const float* W2l = (const float*)d_in[6];
    const float* W2r = (const float*)d_in[7];
    const float* b2  = (const float*)d_in[8];
    const float* Wlp = (const float*)d_in[9];
    const float* blp = (const float*)d_in[10];
    float* out = (float*)d_out;

    long N = in_sizes[0] / 64;
    long E = in_sizes[1] / 2;
    long P = in_sizes[2] / 2;

    float* deg  = (float*)d_ws;            // N
    float* agg1 = deg + N;                 // N*64
    float* agg2 = agg1 + N * 64;           // N*128
    float* h1   = agg2 + N * 128;          // N*128
    float* h2   = h1 + N * 128;            // N*64
    int*   flag = (int*)(h2 + N * 64);     // 1

    // zero deg + agg1 + agg2 in one shot (they are contiguous)
    size_t zero_bytes = sizeof(float) * (size_t)(N + N * 64 + N * 128);
    hipMemsetAsync(d_ws, 0, zero_bytes, stream);

    detect64_kernel<<<1, 1, 0, stream>>>(eidx, flag);

    {
        long total = E * 64;
        unsigned blocks = (unsigned)((total + 255) / 256);
        scatter1_kernel<<<blocks, 256, 0, stream>>>(eidx, flag, x, agg1, deg, E);
    }
    {
        unsigned blocks = (unsigned)((N + NPB - 1) / NPB);
        update1_kernel<<<blocks, 256, 0, stream>>>(x, agg1, deg, W1l, W1r, b1, h1, N);
    }
    {
        long total = E * 128;
        unsigned blocks = (unsigned)((total + 255) / 256);
        scatter2_kernel<<<blocks, 256, 0, stream>>>(eidx, flag, h1, agg2, E);
    }
    {
        unsigned blocks = (unsigned)((N + NPB - 1) / NPB);
        update2_kernel<<<blocks, 256, 0, stream>>>(h1, agg2, deg, W2l, W2r, b2, h2, N);
    }
    {
        unsigned blocks = (unsigned)((P + 255) / 256);
        linkpred_kernel<<<blocks, 256, 0, stream>>>(pairs, flag, h2, Wlp, blp, out, P);
    }
}

// Round 2
// 738.105 us; speedup vs baseline: 2.5051x; 2.5051x over previous
//
#include <hip/hip_runtime.h>
#include <hip/hip_bf16.h>

// GraphSAGE 2-layer + link predictor, CSR-gather formulation (no float atomics).
// detect dtype -> count deg -> scan -> fill CSR -> gather agg1 -> update1(h1)
// -> project(g1 = h1@W2l.T, r1 = h1@W2r.T+b2) -> gather h2 = mean(g1)+r1 -> linkpred

#define NPB 16  // nodes per block in dense kernels

__device__ __forceinline__ long load_idx(const void* p, long i, int is64) {
    if (is64) return (long)((const long long*)p)[i];
    return (long)((const int*)p)[i];
}

// Decide whether index arrays are int64 (odd dwords all zero) or int32.
__global__ void detect64_kernel(const void* eidx, int* flag) {
    const unsigned* u = (const unsigned*)eidx;
    unsigned acc = 0;
    for (int i = 0; i < 128; ++i) acc |= u[2 * i + 1];
    *flag = (acc == 0u) ? 1 : 0;
}

__global__ void count_kernel(const void* eidx, const int* flag, int* cursor, long E) {
    long e = (long)blockIdx.x * 256 + threadIdx.x;
    if (e >= E) return;
    int is64 = *flag;
    long dst = load_idx(eidx, E + e, is64);
    atomicAdd(&cursor[dst], 1);
}

// 1024-elem chunk sums
__global__ void scan_partial_kernel(const int* __restrict__ cnt, int* __restrict__ partial, long N) {
    __shared__ int ts[256];
    int b = blockIdx.x, t = threadIdx.x;
    long base = (long)b * 1024 + (long)t * 4;
    int s = 0;
#pragma unroll
    for (int j = 0; j < 4; ++j) { long i = base + j; if (i < N) s += cnt[i]; }
    ts[t] = s; __syncthreads();
    for (int off = 128; off > 0; off >>= 1) {
        if (t < off) ts[t] += ts[t + off];
        __syncthreads();
    }
    if (t == 0) partial[b] = ts[0];
}

__global__ void scan_root_kernel(int* partial, int* row_start, int nb, long N) {
    int acc = 0;
    for (int i = 0; i < nb; ++i) { int v = partial[i]; partial[i] = acc; acc += v; }
    row_start[N] = acc;
}

__global__ void scan_apply_kernel(const int* __restrict__ cnt, const int* __restrict__ partial,
                                  int* __restrict__ row_start, int* __restrict__ cursor, long N) {
    __shared__ int ts[256];
    int b = blockIdx.x, t = threadIdx.x;
    long base = (long)b * 1024 + (long)t * 4;
    int v[4];
#pragma unroll
    for (int j = 0; j < 4; ++j) { long i = base + j; v[j] = (i < N) ? cnt[i] : 0; }
    int s0 = v[0], s1 = s0 + v[1], s2 = s1 + v[2], s3 = s2 + v[3];
    ts[t] = s3; __syncthreads();
    for (int off = 1; off < 256; off <<= 1) {
        int u = (t >= off) ? ts[t - off] : 0;
        __syncthreads();
        ts[t] += u;
        __syncthreads();
    }
    int toff = ts[t] - s3 + partial[b];
    int ex[4] = {toff, toff + s0, toff + s1, toff + s2};
#pragma unroll
    for (int j = 0; j < 4; ++j) {
        long i = base + j;
        if (i < N) { row_start[i] = ex[j]; cursor[i] = 0; }
    }
}

__global__ void fill_kernel(const void* eidx, const int* flag, const int* __restrict__ row_start,
                            int* __restrict__ cursor, int* __restrict__ csr_src, long E) {
    long e = (long)blockIdx.x * 256 + threadIdx.x;
    if (e >= E) return;
    int is64 = *flag;
    long src = load_idx(eidx, e, is64);
    long dst = load_idx(eidx, E + e, is64);
    int pos = atomicAdd(&cursor[dst], 1);
    csr_src[row_start[dst] + pos] = (int)src;
}

// One wave per node; lane f = feature. Raw neighbor sum of x (64-dim).
__global__ void gather_agg1_kernel(const int* __restrict__ row_start, const int* __restrict__ csr,
                                   const float* __restrict__ x, float* __restrict__ agg1, long N) {
    long gid = (long)blockIdx.x * 256 + threadIdx.x;
    long n = gid >> 6;
    int f = (int)(gid & 63);
    if (n >= N) return;
    int s = row_start[n], e = row_start[n + 1];
    float a0 = 0.f, a1 = 0.f, a2 = 0.f, a3 = 0.f;
    int j = s;
    for (; j + 4 <= e; j += 4) {
        int i0 = csr[j], i1 = csr[j + 1], i2 = csr[j + 2], i3 = csr[j + 3];
        a0 += x[(long)i0 * 64 + f];
        a1 += x[(long)i1 * 64 + f];
        a2 += x[(long)i2 * 64 + f];
        a3 += x[(long)i3 * 64 + f];
    }
    for (; j < e; ++j) a0 += x[(long)csr[j] * 64 + f];
    agg1[n * 64 + f] = (a0 + a1) + (a2 + a3);
}

// h2[n][f] = (sum_nbr g1[src][f]) / max(deg,1) + r1[n][f]
__global__ void gather_h2_kernel(const int* __restrict__ row_start, const int* __restrict__ csr,
                                 const float* __restrict__ g1, const float* __restrict__ r1,
                                 float* __restrict__ h2, long N) {
    long gid = (long)blockIdx.x * 256 + threadIdx.x;
    long n = gid >> 6;
    int f = (int)(gid & 63);
    if (n >= N) return;
    int s = row_start[n], e = row_start[n + 1];
    float a0 = 0.f, a1 = 0.f, a2 = 0.f, a3 = 0.f;
    int j = s;
    for (; j + 4 <= e; j += 4) {
        int i0 = csr[j], i1 = csr[j + 1], i2 = csr[j + 2], i3 = csr[j + 3];
        a0 += g1[(long)i0 * 64 + f];
        a1 += g1[(long)i1 * 64 + f];
        a2 += g1[(long)i2 * 64 + f];
        a3 += g1[(long)i3 * 64 + f];
    }
    for (; j < e; ++j) a0 += g1[(long)csr[j] * 64 + f];
    float sum = (a0 + a1) + (a2 + a3);
    float deg = (float)(e - s);
    h2[n * 64 + f] = sum / fmaxf(deg, 1.0f) + r1[n * 64 + f];
}

// h1[n][o] = relu( sum_k W1l[o][k]*(agg1[n][k]/deg) + W1r[o][k]*x[n][k] + b1[o] )
__global__ void update1_kernel(const float* __restrict__ x,
                               const float* __restrict__ agg1,
                               const int* __restrict__ rs,
                               const float* __restrict__ W1l,
                               const float* __restrict__ W1r,
                               const float* __restrict__ b1,
                               float* __restrict__ h1, long N) {
    __shared__ float wl[64][129];   // [k][o], padded
    __shared__ float wr[64][129];
    __shared__ float xs[NPB][64];
    __shared__ float as[NPB][64];
    __shared__ float bs[128];
    int tid = threadIdx.x;
    for (int idx = tid; idx < 128 * 64; idx += 256) {
        int o = idx >> 6, k = idx & 63;
        wl[k][o] = W1l[idx];
        wr[k][o] = W1r[idx];
    }
    if (tid < 128) bs[tid] = b1[tid];
    long node0 = (long)blockIdx.x * NPB;
    for (int idx = tid; idx < NPB * 64; idx += 256) {
        int nl = idx >> 6, k = idx & 63;
        long n = node0 + nl;
        float xv = 0.f, av = 0.f;
        if (n < N) {
            xv = x[n * 64 + k];
            float d = (float)(rs[n + 1] - rs[n]);
            av = agg1[n * 64 + k] / fmaxf(d, 1.0f);
        }
        xs[nl][k] = xv;
        as[nl][k] = av;
    }
    __syncthreads();
    int o = tid & 127;
    int half = tid >> 7;
    for (int i = 0; i < NPB / 2; ++i) {
        int nl = half + 2 * i;
        long n = node0 + nl;
        if (n >= N) continue;
        float acc = bs[o];
#pragma unroll
        for (int k = 0; k < 64; ++k)
            acc += wl[k][o] * as[nl][k] + wr[k][o] * xs[nl][k];
        h1[n * 128 + o] = fmaxf(acc, 0.f);
    }
}

// g1 = h1 @ W2l.T ; r1 = h1 @ W2r.T + b2
__global__ void project_kernel(const float* __restrict__ h1,
                               const float* __restrict__ W2l,
                               const float* __restrict__ W2r,
                               const float* __restrict__ b2,
                               float* __restrict__ g1, float* __restrict__ r1, long N) {
    __shared__ float wl[128][65];   // [k][o], padded
    __shared__ float wr[128][65];
    __shared__ float hs[NPB][128];
    __shared__ float bs[64];
    int tid = threadIdx.x;
    for (int idx = tid; idx < 64 * 128; idx += 256) {
        int o = idx >> 7, k = idx & 127;
        wl[k][o] = W2l[idx];
        wr[k][o] = W2r[idx];
    }
    if (tid < 64) bs[tid] = b2[tid];
    long node0 = (long)blockIdx.x * NPB;
    for (int idx = tid; idx < NPB * 128; idx += 256) {
        int nl = idx >> 7, k = idx & 127;
        long n = node0 + nl;
        hs[nl][k] = (n < N) ? h1[n * 128 + k] : 0.f;
    }
    __syncthreads();
    int o = tid & 63;
    int q = tid >> 6;
    for (int i = 0; i < NPB / 4; ++i) {
        int nl = q + 4 * i;
        long n = node0 + nl;
        if (n >= N) continue;
        float ag = 0.f, ar = bs[o];
#pragma unroll
        for (int k = 0; k < 128; ++k) {
            float h = hs[nl][k];
            ag += wl[k][o] * h;
            ar += wr[k][o] * h;
        }
        g1[n * 64 + o] = ag;
        r1[n * 64 + o] = ar;
    }
}

__global__ void linkpred_kernel(const void* pairs, const int* flag,
                                const float* __restrict__ h2,
                                const float* __restrict__ Wlp,
                                const float* __restrict__ blp,
                                float* __restrict__ out, long P) {
    __shared__ float w[128];
    __shared__ float bb;
    int tid = threadIdx.x;
    if (tid < 128) w[tid] = Wlp[tid];
    if (tid == 0) bb = blp[0];
    __syncthreads();
    long p = (long)blockIdx.x * 256 + tid;
    if (p >= P) return;
    int is64 = *flag;
    long s = load_idx(pairs, 2 * p, is64);
    long d = load_idx(pairs, 2 * p + 1, is64);
    float acc = bb;
    const float4* hs = (const float4*)(h2 + s * 64);
    const float4* hd = (const float4*)(h2 + d * 64);
#pragma unroll
    for (int j = 0; j < 16; ++j) {
        float4 v = hs[j];
        acc += v.x * w[j * 4] + v.y * w[j * 4 + 1] + v.z * w[j * 4 + 2] + v.w * w[j * 4 + 3];
    }
#pragma unroll
    for (int j = 0; j < 16; ++j) {
        float4 v = hd[j];
        acc += v.x * w[64 + j * 4] + v.y * w[64 + j * 4 + 1] + v.z * w[64 + j * 4 + 2] + v.w * w[64 + j * 4 + 3];
    }
    out[p] = 1.0f / (1.0f + expf(-acc));
}

extern "C" void kernel_launch(void* const* d_in, const int* in_sizes, int n_in,
                              void* d_out, int out_size, void* d_ws, size_t ws_size,
                              hipStream_t stream) {
    const float* x    = (const float*)d_in[0];
    const void*  eidx  = d_in[1];
    const void*  pairs = d_in[2];
    const float* W1l = (const float*)d_in[3];
    const float* W1r = (const float*)d_in[4];
    const float* b1  = (const float*)d_in[5];
    const float* W2l = (const float*)d_in[6];
    const float* W2r = (const float*)d_in[7];
    const float* b2  = (const float*)d_in[8];
    const float* Wlp = (const float*)d_in[9];
    const float* blp = (const float*)d_in[10];
    float* out = (float*)d_out;

    long N = in_sizes[0] / 64;
    long E = in_sizes[1] / 2;
    long P = in_sizes[2] / 2;

    char* w = (char*)d_ws;
    auto alloc = [&](size_t bytes) {
        char* p = w;
        w += (bytes + 255) & ~(size_t)255;
        return p;
    };
    int* row_start = (int*)alloc((N + 1) * sizeof(int));
    int* cursor    = (int*)alloc(N * sizeof(int));
    int* csr_src   = (int*)alloc(E * sizeof(int));
    int* partial   = (int*)alloc(1024 * sizeof(int));
    int* flag      = (int*)alloc(64);
    float* agg1    = (float*)alloc((size_t)N * 64 * sizeof(float)); // reused as h2
    float* h1      = (float*)alloc((size_t)N * 128 * sizeof(float));
    float* g1      = (float*)alloc((size_t)N * 64 * sizeof(float));
    float* r1      = (float*)alloc((size_t)N * 64 * sizeof(float));
    float* h2      = agg1;  // agg1 dead after update1

    hipMemsetAsync(cursor, 0, N * sizeof(int), stream);
    detect64_kernel<<<1, 1, 0, stream>>>(eidx, flag);

    unsigned eblocks = (unsigned)((E + 255) / 256);
    count_kernel<<<eblocks, 256, 0, stream>>>(eidx, flag, cursor, E);

    int NB = (int)((N + 1023) / 1024);
    scan_partial_kernel<<<NB, 256, 0, stream>>>(cursor, partial, N);
    scan_root_kernel<<<1, 1, 0, stream>>>(partial, row_start, NB, N);
    scan_apply_kernel<<<NB, 256, 0, stream>>>(cursor, partial, row_start, cursor, N);

    fill_kernel<<<eblocks, 256, 0, stream>>>(eidx, flag, row_start, cursor, csr_src, E);

    unsigned nwaves_blocks = (unsigned)((N * 64 + 255) / 256);
    gather_agg1_kernel<<<nwaves_blocks, 256, 0, stream>>>(row_start, csr_src, x, agg1, N);

    unsigned nodeblocks = (unsigned)((N + NPB - 1) / NPB);
    update1_kernel<<<nodeblocks, 256, 0, stream>>>(x, agg1, row_start, W1l, W1r, b1, h1, N);
    project_kernel<<<nodeblocks, 256, 0, stream>>>(h1, W2l, W2r, b2, g1, r1, N);

    gather_h2_kernel<<<nwaves_blocks, 256, 0, stream>>>(row_start, csr_src, g1, r1, h2, N);

    unsigned pblocks = (unsigned)((P + 255) / 256);
    linkpred_kernel<<<pblocks, 256, 0, stream>>>(pairs, flag, h2, Wlp, blp, out, P);
}

// Round 3
// 569.478 us; speedup vs baseline: 3.2469x; 1.2961x over previous
//
#include <hip/hip_runtime.h>
#include <hip/hip_bf16.h>

// GraphSAGE 2-layer + link predictor, CSR-gather + register-tiled dense layers.
// detect dtype -> count deg -> scan -> fill CSR -> gather agg1 -> update1(h1)
// -> project(g1 = h1@W2l.T, r1 = h1@W2r.T+b2) -> gather h2 = mean(g1)+r1 -> linkpred

__device__ __forceinline__ long load_idx(const void* p, long i, int is64) {
    if (is64) return (long)((const long long*)p)[i];
    return (long)((const int*)p)[i];
}

// Decide whether index arrays are int64 (odd dwords all zero) or int32.
__global__ void detect64_kernel(const void* eidx, int* flag) {
    const unsigned* u = (const unsigned*)eidx;
    unsigned acc = 0;
    for (int i = 0; i < 128; ++i) acc |= u[2 * i + 1];
    *flag = (acc == 0u) ? 1 : 0;
}

__global__ void count_kernel(const void* eidx, const int* flag, int* cursor, long E) {
    long e = (long)blockIdx.x * 256 + threadIdx.x;
    if (e >= E) return;
    int is64 = *flag;
    long dst = load_idx(eidx, E + e, is64);
    atomicAdd(&cursor[dst], 1);
}

// 1024-elem chunk sums
__global__ void scan_partial_kernel(const int* __restrict__ cnt, int* __restrict__ partial, long N) {
    __shared__ int ts[256];
    int b = blockIdx.x, t = threadIdx.x;
    long base = (long)b * 1024 + (long)t * 4;
    int s = 0;
#pragma unroll
    for (int j = 0; j < 4; ++j) { long i = base + j; if (i < N) s += cnt[i]; }
    ts[t] = s; __syncthreads();
    for (int off = 128; off > 0; off >>= 1) {
        if (t < off) ts[t] += ts[t + off];
        __syncthreads();
    }
    if (t == 0) partial[b] = ts[0];
}

__global__ void scan_root_kernel(int* partial, int* row_start, int nb, long N) {
    int acc = 0;
    for (int i = 0; i < nb; ++i) { int v = partial[i]; partial[i] = acc; acc += v; }
    row_start[N] = acc;
}

__global__ void scan_apply_kernel(const int* __restrict__ cnt, const int* __restrict__ partial,
                                  int* __restrict__ row_start, int* __restrict__ cursor, long N) {
    __shared__ int ts[256];
    int b = blockIdx.x, t = threadIdx.x;
    long base = (long)b * 1024 + (long)t * 4;
    int v[4];
#pragma unroll
    for (int j = 0; j < 4; ++j) { long i = base + j; v[j] = (i < N) ? cnt[i] : 0; }
    int s0 = v[0], s1 = s0 + v[1], s2 = s1 + v[2], s3 = s2 + v[3];
    ts[t] = s3; __syncthreads();
    for (int off = 1; off < 256; off <<= 1) {
        int u = (t >= off) ? ts[t - off] : 0;
        __syncthreads();
        ts[t] += u;
        __syncthreads();
    }
    int toff = ts[t] - s3 + partial[b];
    int ex[4] = {toff, toff + s0, toff + s1, toff + s2};
#pragma unroll
    for (int j = 0; j < 4; ++j) {
        long i = base + j;
        if (i < N) { row_start[i] = ex[j]; cursor[i] = 0; }
    }
}

__global__ void fill_kernel(const void* eidx, const int* flag, const int* __restrict__ row_start,
                            int* __restrict__ cursor, int* __restrict__ csr_src, long E) {
    long e = (long)blockIdx.x * 256 + threadIdx.x;
    if (e >= E) return;
    int is64 = *flag;
    long src = load_idx(eidx, e, is64);
    long dst = load_idx(eidx, E + e, is64);
    int pos = atomicAdd(&cursor[dst], 1);
    csr_src[row_start[dst] + pos] = (int)src;
}

// One wave per node; lane f = feature. Raw neighbor sum of x (64-dim).
__global__ void gather_agg1_kernel(const int* __restrict__ row_start, const int* __restrict__ csr,
                                   const float* __restrict__ x, float* __restrict__ agg1, long N) {
    long gid = (long)blockIdx.x * 256 + threadIdx.x;
    long n = gid >> 6;
    int f = (int)(gid & 63);
    if (n >= N) return;
    int s = row_start[n], e = row_start[n + 1];
    float a0 = 0.f, a1 = 0.f, a2 = 0.f, a3 = 0.f;
    int j = s;
    for (; j + 4 <= e; j += 4) {
        int i0 = csr[j], i1 = csr[j + 1], i2 = csr[j + 2], i3 = csr[j + 3];
        a0 += x[(long)i0 * 64 + f];
        a1 += x[(long)i1 * 64 + f];
        a2 += x[(long)i2 * 64 + f];
        a3 += x[(long)i3 * 64 + f];
    }
    for (; j < e; ++j) a0 += x[(long)csr[j] * 64 + f];
    agg1[n * 64 + f] = (a0 + a1) + (a2 + a3);
}

// h2[n][f] = (sum_nbr g1[src][f]) / max(deg,1) + r1[n][f]
__global__ void gather_h2_kernel(const int* __restrict__ row_start, const int* __restrict__ csr,
                                 const float* __restrict__ g1, const float* __restrict__ r1,
                                 float* __restrict__ h2, long N) {
    long gid = (long)blockIdx.x * 256 + threadIdx.x;
    long n = gid >> 6;
    int f = (int)(gid & 63);
    if (n >= N) return;
    int s = row_start[n], e = row_start[n + 1];
    float a0 = 0.f, a1 = 0.f, a2 = 0.f, a3 = 0.f;
    int j = s;
    for (; j + 4 <= e; j += 4) {
        int i0 = csr[j], i1 = csr[j + 1], i2 = csr[j + 2], i3 = csr[j + 3];
        a0 += g1[(long)i0 * 64 + f];
        a1 += g1[(long)i1 * 64 + f];
        a2 += g1[(long)i2 * 64 + f];
        a3 += g1[(long)i3 * 64 + f];
    }
    for (; j < e; ++j) a0 += g1[(long)csr[j] * 64 + f];
    float sum = (a0 + a1) + (a2 + a3);
    float deg = (float)(e - s);
    h2[n * 64 + f] = sum / fmaxf(deg, 1.0f) + r1[n * 64 + f];
}

// ---------------- register-tiled dense layers ----------------

// update1: h1[n][o] = relu( sum_k W1l[o][k]*(agg1[n][k]/deg) + W1r[o][k]*x[n][k] + b1[o] )
// tile: 32 nodes x 128 outputs, 256 threads = 32 o-threads (4 o each) x 8 n-threads (4 n each)
__global__ __launch_bounds__(256, 2) void update1_kernel(
        const float* __restrict__ x, const float* __restrict__ agg1,
        const int* __restrict__ rs,
        const float* __restrict__ W1l, const float* __restrict__ W1r,
        const float* __restrict__ b1, float* __restrict__ h1, long N) {
    __shared__ float xs[32][64];
    __shared__ float as[32][64];
    __shared__ float wl[32][132];   // [k-local][o], pad 4: aligned f4, 4-way stage-write conflict only
    __shared__ float wr[32][132];
    __shared__ float bs[128];
    int tid = threadIdx.x;
    long node0 = (long)blockIdx.x * 32;

    // stage node tile: 32 rows x 16 quads = 512 quads
#pragma unroll
    for (int it = 0; it < 2; ++it) {
        int q = tid + it * 256;
        int n = q >> 4, kq = q & 15;
        long nn = node0 + n;
        float4 xv = make_float4(0.f, 0.f, 0.f, 0.f), av = xv;
        if (nn < N) {
            xv = *(const float4*)&x[nn * 64 + kq * 4];
            float d = fmaxf((float)(rs[nn + 1] - rs[nn]), 1.0f);
            float4 t = *(const float4*)&agg1[nn * 64 + kq * 4];
            av = make_float4(t.x / d, t.y / d, t.z / d, t.w / d);
        }
        *(float4*)&xs[n][kq * 4] = xv;
        *(float4*)&as[n][kq * 4] = av;
    }
    if (tid < 128) bs[tid] = b1[tid];

    int ot = tid & 31;    // output group: o = ot*4..ot*4+3
    int nt = tid >> 5;    // node group:  n = nt*4..nt*4+3
    float acc[4][4] = {{0.f}};

    for (int half = 0; half < 2; ++half) {
        __syncthreads();
        // stage transposed weights for k in [half*32, half*32+32)
#pragma unroll
        for (int it = 0; it < 16; ++it) {
            int q = tid + it * 256;          // 0..4095
            int o = q >> 5, kk = q & 31;
            wl[kk][o] = W1l[o * 64 + half * 32 + kk];
            wr[kk][o] = W1r[o * 64 + half * 32 + kk];
        }
        __syncthreads();
#pragma unroll
        for (int kq = 0; kq < 8; ++kq) {
            float4 wlv[4], wrv[4];
#pragma unroll
            for (int j = 0; j < 4; ++j) {
                wlv[j] = *(float4*)&wl[kq * 4 + j][ot * 4];
                wrv[j] = *(float4*)&wr[kq * 4 + j][ot * 4];
            }
#pragma unroll
            for (int i = 0; i < 4; ++i) {
                int n = nt * 4 + i;
                int kbase = half * 32 + kq * 4;
                (void)kbase;
                float4 a = *(float4*)&as[n][kq * 4 + half * 0];
                float4 xv = *(float4*)&xs[n][kq * 4];
                // NOTE: as/xs hold all 64 k; local index = half*32 + kq*4
                a = *(float4*)&as[n][half * 32 + kq * 4];
                xv = *(float4*)&xs[n][half * 32 + kq * 4];
#define FMA4(AC, XC, J) \
                acc[i][0] += AC * wlv[J].x + XC * wrv[J].x; \
                acc[i][1] += AC * wlv[J].y + XC * wrv[J].y; \
                acc[i][2] += AC * wlv[J].z + XC * wrv[J].z; \
                acc[i][3] += AC * wlv[J].w + XC * wrv[J].w;
                FMA4(a.x, xv.x, 0)
                FMA4(a.y, xv.y, 1)
                FMA4(a.z, xv.z, 2)
                FMA4(a.w, xv.w, 3)
#undef FMA4
            }
        }
    }
#pragma unroll
    for (int i = 0; i < 4; ++i) {
        long nn = node0 + nt * 4 + i;
        if (nn >= N) continue;
        float4 o4;
        o4.x = fmaxf(acc[i][0] + bs[ot * 4 + 0], 0.f);
        o4.y = fmaxf(acc[i][1] + bs[ot * 4 + 1], 0.f);
        o4.z = fmaxf(acc[i][2] + bs[ot * 4 + 2], 0.f);
        o4.w = fmaxf(acc[i][3] + bs[ot * 4 + 3], 0.f);
        *(float4*)&h1[nn * 128 + ot * 4] = o4;
    }
}

// project: g1 = h1 @ W2l.T ; r1 = h1 @ W2r.T + b2
// tile: 64 nodes x 64 outputs, 256 threads = 16 o-threads (4 o) x 16 n-threads (4 n)
__global__ __launch_bounds__(256, 2) void project_kernel(
        const float* __restrict__ h1,
        const float* __restrict__ W2l, const float* __restrict__ W2r,
        const float* __restrict__ b2,
        float* __restrict__ g1, float* __restrict__ r1, long N) {
    __shared__ float hs[64][64];    // k-half of h1 tile
    __shared__ float wl[64][68];    // [k-local][o], pad 4
    __shared__ float wr[64][68];
    __shared__ float bs[64];
    int tid = threadIdx.x;
    long node0 = (long)blockIdx.x * 64;
    if (tid < 64) bs[tid] = b2[tid];

    int ot = tid & 15;    // o = ot*4..ot*4+3
    int nt = tid >> 4;    // n = nt*4..nt*4+3
    float ag[4][4] = {{0.f}};
    float ar[4][4] = {{0.f}};

    for (int half = 0; half < 2; ++half) {
        __syncthreads();
        // stage h1 k-half: 64 rows x 16 quads = 1024 quads
#pragma unroll
        for (int it = 0; it < 4; ++it) {
            int q = tid + it * 256;
            int n = q >> 4, kq = q & 15;
            long nn = node0 + n;
            float4 hv = make_float4(0.f, 0.f, 0.f, 0.f);
            if (nn < N) hv = *(const float4*)&h1[nn * 128 + half * 64 + kq * 4];
            *(float4*)&hs[n][kq * 4] = hv;
        }
        // stage transposed weights for k in [half*64, half*64+64): 64 o x 64 k
#pragma unroll
        for (int it = 0; it < 16; ++it) {
            int q = tid + it * 256;          // 0..4095
            int o = q >> 6, kk = q & 63;
            wl[kk][o] = W2l[o * 128 + half * 64 + kk];
            wr[kk][o] = W2r[o * 128 + half * 64 + kk];
        }
        __syncthreads();
#pragma unroll
        for (int kq = 0; kq < 16; ++kq) {
            float4 wlv[4], wrv[4];
#pragma unroll
            for (int j = 0; j < 4; ++j) {
                wlv[j] = *(float4*)&wl[kq * 4 + j][ot * 4];
                wrv[j] = *(float4*)&wr[kq * 4 + j][ot * 4];
            }
#pragma unroll
            for (int i = 0; i < 4; ++i) {
                int n = nt * 4 + i;
                float4 h = *(float4*)&hs[n][kq * 4];
#define FMA4P(HC, J) \
                ag[i][0] += HC * wlv[J].x;  ar[i][0] += HC * wrv[J].x; \
                ag[i][1] += HC * wlv[J].y;  ar[i][1] += HC * wrv[J].y; \
                ag[i][2] += HC * wlv[J].z;  ar[i][2] += HC * wrv[J].z; \
                ag[i][3] += HC * wlv[J].w;  ar[i][3] += HC * wrv[J].w;
                FMA4P(h.x, 0)
                FMA4P(h.y, 1)
                FMA4P(h.z, 2)
                FMA4P(h.w, 3)
#undef FMA4P
            }
        }
    }
#pragma unroll
    for (int i = 0; i < 4; ++i) {
        long nn = node0 + nt * 4 + i;
        if (nn >= N) continue;
        float4 gv, rv;
        gv.x = ag[i][0]; gv.y = ag[i][1]; gv.z = ag[i][2]; gv.w = ag[i][3];
        rv.x = ar[i][0] + bs[ot * 4 + 0];
        rv.y = ar[i][1] + bs[ot * 4 + 1];
        rv.z = ar[i][2] + bs[ot * 4 + 2];
        rv.w = ar[i][3] + bs[ot * 4 + 3];
        *(float4*)&g1[nn * 64 + ot * 4] = gv;
        *(float4*)&r1[nn * 64 + ot * 4] = rv;
    }
}

__global__ void linkpred_kernel(const void* pairs, const int* flag,
                                const float* __restrict__ h2,
                                const float* __restrict__ Wlp,
                                const float* __restrict__ blp,
                                float* __restrict__ out, long P) {
    __shared__ float w[128];
    __shared__ float bb;
    int tid = threadIdx.x;
    if (tid < 128) w[tid] = Wlp[tid];
    if (tid == 0) bb = blp[0];
    __syncthreads();
    long p = (long)blockIdx.x * 256 + tid;
    if (p >= P) return;
    int is64 = *flag;
    long s = load_idx(pairs, 2 * p, is64);
    long d = load_idx(pairs, 2 * p + 1, is64);
    float acc = bb;
    const float4* hs = (const float4*)(h2 + s * 64);
    const float4* hd = (const float4*)(h2 + d * 64);
#pragma unroll
    for (int j = 0; j < 16; ++j) {
        float4 v = hs[j];
        acc += v.x * w[j * 4] + v.y * w[j * 4 + 1] + v.z * w[j * 4 + 2] + v.w * w[j * 4 + 3];
    }
#pragma unroll
    for (int j = 0; j < 16; ++j) {
        float4 v = hd[j];
        acc += v.x * w[64 + j * 4] + v.y * w[64 + j * 4 + 1] + v.z * w[64 + j * 4 + 2] + v.w * w[64 + j * 4 + 3];
    }
    out[p] = 1.0f / (1.0f + expf(-acc));
}

extern "C" void kernel_launch(void* const* d_in, const int* in_sizes, int n_in,
                              void* d_out, int out_size, void* d_ws, size_t ws_size,
                              hipStream_t stream) {
    const float* x    = (const float*)d_in[0];
    const void*  eidx  = d_in[1];
    const void*  pairs = d_in[2];
    const float* W1l = (const float*)d_in[3];
    const float* W1r = (const float*)d_in[4];
    const float* b1  = (const float*)d_in[5];
    const float* W2l = (const float*)d_in[6];
    const float* W2r = (const float*)d_in[7];
    const float* b2  = (const float*)d_in[8];
    const float* Wlp = (const float*)d_in[9];
    const float* blp = (const float*)d_in[10];
    float* out = (float*)d_out;

    long N = in_sizes[0] / 64;
    long E = in_sizes[1] / 2;
    long P = in_sizes[2] / 2;

    char* w = (char*)d_ws;
    auto alloc = [&](size_t bytes) {
        char* p = w;
        w += (bytes + 255) & ~(size_t)255;
        return p;
    };
    int* row_start = (int*)alloc((N + 1) * sizeof(int));
    int* cursor    = (int*)alloc(N * sizeof(int));
    int* csr_src   = (int*)alloc(E * sizeof(int));
    int* partial   = (int*)alloc(1024 * sizeof(int));
    int* flag      = (int*)alloc(64);
    float* agg1    = (float*)alloc((size_t)N * 64 * sizeof(float)); // reused as h2
    float* h1      = (float*)alloc((size_t)N * 128 * sizeof(float));
    float* g1      = (float*)alloc((size_t)N * 64 * sizeof(float));
    float* r1      = (float*)alloc((size_t)N * 64 * sizeof(float));
    float* h2      = agg1;  // agg1 dead after update1

    hipMemsetAsync(cursor, 0, N * sizeof(int), stream);
    detect64_kernel<<<1, 1, 0, stream>>>(eidx, flag);

    unsigned eblocks = (unsigned)((E + 255) / 256);
    count_kernel<<<eblocks, 256, 0, stream>>>(eidx, flag, cursor, E);

    int NB = (int)((N + 1023) / 1024);
    scan_partial_kernel<<<NB, 256, 0, stream>>>(cursor, partial, N);
    scan_root_kernel<<<1, 1, 0, stream>>>(partial, row_start, NB, N);
    scan_apply_kernel<<<NB, 256, 0, stream>>>(cursor, partial, row_start, cursor, N);

    fill_kernel<<<eblocks, 256, 0, stream>>>(eidx, flag, row_start, cursor, csr_src, E);

    unsigned nwaves_blocks = (unsigned)((N * 64 + 255) / 256);
    gather_agg1_kernel<<<nwaves_blocks, 256, 0, stream>>>(row_start, csr_src, x, agg1, N);

    unsigned u1blocks = (unsigned)((N + 31) / 32);
    update1_kernel<<<u1blocks, 256, 0, stream>>>(x, agg1, row_start, W1l, W1r, b1, h1, N);
    unsigned pjblocks = (unsigned)((N + 63) / 64);
    project_kernel<<<pjblocks, 256, 0, stream>>>(h1, W2l, W2r, b2, g1, r1, N);

    gather_h2_kernel<<<nwaves_blocks, 256, 0, stream>>>(row_start, csr_src, g1, r1, h2, N);

    unsigned pblocks = (unsigned)((P + 255) / 256);
    linkpred_kernel<<<pblocks, 256, 0, stream>>>(pairs, flag, h2, Wlp, blp, out, P);
}

// Round 4
// 360.282 us; speedup vs baseline: 5.1322x; 1.5806x over previous
//
#include <hip/hip_runtime.h>

// GraphSAGE 2-layer + link predictor.
// CSR build (count/scan/fill) -> xcast (x->bf16 into xa own-half)
// -> gather_xa (mean of neighbors, bf16, into xa agg-half)
// -> gemm<0>: h1 = relu(xa @ [W1l|W1r].T + b1)            (bf16 MFMA)
// -> gemm<1>: gr = [h1@W2l.T | h1@W2r.T + b2]             (bf16 MFMA)
// -> gather_h2: h2 = mean_nbr(gr[:, :64]) + gr[n, 64:]    (bf16)
// -> linkpred: sigmoid(concat(h2[s],h2[d]) . Wlp + blp)

typedef __attribute__((ext_vector_type(8))) short bf16x8;
typedef __attribute__((ext_vector_type(4))) float f32x4;

__device__ __forceinline__ unsigned short f2bf(float f) {
    unsigned u = __float_as_uint(f);
    u = u + 0x7fffu + ((u >> 16) & 1u);   // RTNE
    return (unsigned short)(u >> 16);
}
__device__ __forceinline__ float b2f(unsigned short s) {
    return __uint_as_float(((unsigned)s) << 16);
}

__device__ __forceinline__ long load_idx(const void* p, long i, int is64) {
    if (is64) return (long)((const long long*)p)[i];
    return (long)((const int*)p)[i];
}

__global__ void detect64_kernel(const void* eidx, int* flag) {
    const unsigned* u = (const unsigned*)eidx;
    unsigned acc = 0;
    for (int i = 0; i < 128; ++i) acc |= u[2 * i + 1];
    *flag = (acc == 0u) ? 1 : 0;
}

__global__ void count_kernel(const void* eidx, const int* flag, int* cursor, long E) {
    long e = (long)blockIdx.x * 256 + threadIdx.x;
    if (e >= E) return;
    int is64 = *flag;
    long dst = load_idx(eidx, E + e, is64);
    atomicAdd(&cursor[dst], 1);
}

__global__ void scan_partial_kernel(const int* __restrict__ cnt, int* __restrict__ partial, long N) {
    __shared__ int ts[256];
    int b = blockIdx.x, t = threadIdx.x;
    long base = (long)b * 1024 + (long)t * 4;
    int s = 0;
#pragma unroll
    for (int j = 0; j < 4; ++j) { long i = base + j; if (i < N) s += cnt[i]; }
    ts[t] = s; __syncthreads();
    for (int off = 128; off > 0; off >>= 1) {
        if (t < off) ts[t] += ts[t + off];
        __syncthreads();
    }
    if (t == 0) partial[b] = ts[0];
}

__global__ void scan_root_kernel(int* partial, int* row_start, int nb, long N) {
    int acc = 0;
    for (int i = 0; i < nb; ++i) { int v = partial[i]; partial[i] = acc; acc += v; }
    row_start[N] = acc;
}

__global__ void scan_apply_kernel(const int* __restrict__ cnt, const int* __restrict__ partial,
                                  int* __restrict__ row_start, int* __restrict__ cursor, long N) {
    __shared__ int ts[256];
    int b = blockIdx.x, t = threadIdx.x;
    long base = (long)b * 1024 + (long)t * 4;
    int v[4];
#pragma unroll
    for (int j = 0; j < 4; ++j) { long i = base + j; v[j] = (i < N) ? cnt[i] : 0; }
    int s0 = v[0], s1 = s0 + v[1], s2 = s1 + v[2], s3 = s2 + v[3];
    ts[t] = s3; __syncthreads();
    for (int off = 1; off < 256; off <<= 1) {
        int u = (t >= off) ? ts[t - off] : 0;
        __syncthreads();
        ts[t] += u;
        __syncthreads();
    }
    int toff = ts[t] - s3 + partial[b];
    int ex[4] = {toff, toff + s0, toff + s1, toff + s2};
#pragma unroll
    for (int j = 0; j < 4; ++j) {
        long i = base + j;
        if (i < N) { row_start[i] = ex[j]; cursor[i] = 0; }
    }
}

__global__ void fill_kernel(const void* eidx, const int* flag, const int* __restrict__ row_start,
                            int* __restrict__ cursor, int* __restrict__ csr_src, long E) {
    long e = (long)blockIdx.x * 256 + threadIdx.x;
    if (e >= E) return;
    int is64 = *flag;
    long src = load_idx(eidx, e, is64);
    long dst = load_idx(eidx, E + e, is64);
    int pos = atomicAdd(&cursor[dst], 1);
    csr_src[row_start[dst] + pos] = (int)src;
}

// x (f32) -> xa[n][64+f] (bf16). One thread per 4 floats.
__global__ void xcast_kernel(const float* __restrict__ x, unsigned short* __restrict__ xa, long N) {
    long t = (long)blockIdx.x * 256 + threadIdx.x;
    long n = t >> 4;
    int q = (int)(t & 15);
    if (n >= N) return;
    float4 v = *(const float4*)&x[n * 64 + q * 4];
    uint2 u;
    u.x = (unsigned)f2bf(v.x) | ((unsigned)f2bf(v.y) << 16);
    u.y = (unsigned)f2bf(v.z) | ((unsigned)f2bf(v.w) << 16);
    *(uint2*)&xa[n * 128 + 64 + q * 4] = u;
}

// One wave per node; lane f: xa[n][f] = bf16( mean_nbr x_bf16[src][f] )
__global__ void gather_xa_kernel(const int* __restrict__ row_start, const int* __restrict__ csr,
                                 unsigned short* __restrict__ xa, long N) {
    long gid = (long)blockIdx.x * 256 + threadIdx.x;
    long n = gid >> 6;
    int f = (int)(gid & 63);
    if (n >= N) return;
    int s = row_start[n], e = row_start[n + 1];
    float a0 = 0.f, a1 = 0.f, a2 = 0.f, a3 = 0.f;
    int j = s;
    for (; j + 4 <= e; j += 4) {
        int i0 = csr[j], i1 = csr[j + 1], i2 = csr[j + 2], i3 = csr[j + 3];
        a0 += b2f(xa[(long)i0 * 128 + 64 + f]);
        a1 += b2f(xa[(long)i1 * 128 + 64 + f]);
        a2 += b2f(xa[(long)i2 * 128 + 64 + f]);
        a3 += b2f(xa[(long)i3 * 128 + 64 + f]);
    }
    for (; j < e; ++j) a0 += b2f(xa[(long)csr[j] * 128 + 64 + f]);
    float sum = (a0 + a1) + (a2 + a3);
    float deg = (float)(e - s);
    xa[n * 128 + f] = f2bf(sum / fmaxf(deg, 1.0f));
}

// h2[n][f] = bf16( mean_nbr gr[src][f] + gr[n][64+f] )
__global__ void gather_h2_kernel(const int* __restrict__ row_start, const int* __restrict__ csr,
                                 const unsigned short* __restrict__ gr,
                                 unsigned short* __restrict__ h2, long N) {
    long gid = (long)blockIdx.x * 256 + threadIdx.x;
    long n = gid >> 6;
    int f = (int)(gid & 63);
    if (n >= N) return;
    int s = row_start[n], e = row_start[n + 1];
    float a0 = 0.f, a1 = 0.f, a2 = 0.f, a3 = 0.f;
    int j = s;
    for (; j + 4 <= e; j += 4) {
        int i0 = csr[j], i1 = csr[j + 1], i2 = csr[j + 2], i3 = csr[j + 3];
        a0 += b2f(gr[(long)i0 * 128 + f]);
        a1 += b2f(gr[(long)i1 * 128 + f]);
        a2 += b2f(gr[(long)i2 * 128 + f]);
        a3 += b2f(gr[(long)i3 * 128 + f]);
    }
    for (; j < e; ++j) a0 += b2f(gr[(long)csr[j] * 128 + f]);
    float sum = (a0 + a1) + (a2 + a3);
    float deg = (float)(e - s);
    h2[n * 64 + f] = f2bf(sum / fmaxf(deg, 1.0f) + b2f(gr[n * 128 + 64 + f]));
}

// ---------------- MFMA GEMM: C = act(A @ W'.T + b') ----------------
// A: N_pad x 128 bf16 row-major. W' is 128x128:
//   MODE 0 (layer1): W'[o][k] = k<64 ? Wa[o][k] : Wb[o][k-64]   (Wa,Wb are 128x64)
//   MODE 1 (layer2): W'[o][k] = o<64 ? Wa[o][k] : Wb[o-64][k]   (Wa,Wb are 64x128)
// bias: MODE 0: bias[o] (128);  MODE 1: o<64 ? 0 : bias[o-64] (64)
// Per block: 256 thr = 4 waves x 32 nodes; each wave: 2 mtiles x 8 otiles x 4 ksteps.
template <int MODE>
__global__ void gemm_kernel(const unsigned short* __restrict__ A,
                            const float* __restrict__ Wa, const float* __restrict__ Wb,
                            const float* __restrict__ bias,
                            unsigned short* __restrict__ C, long N, int relu) {
    __shared__ unsigned short wlds[128 * 128];  // bf16, XOR-swizzled: idx ^= (o&7)<<3
    __shared__ float bs[128];
    int tid = threadIdx.x;

    // stage W' -> LDS bf16 (coalesced global reads; swizzled scalar LDS writes)
    for (int i = tid; i < 8192; i += 256) {
        float f = Wa[i];
        int o, k;
        if (MODE == 0) { o = i >> 6; k = i & 63; }          // Wa = W1l (128x64), k-low half
        else           { o = i >> 7; k = i & 127; }         // Wa = W2l (64x128),  o-low half
        int idx = (o * 128 + k) ^ ((o & 7) << 3);
        wlds[idx] = f2bf(f);
    }
    for (int i = tid; i < 8192; i += 256) {
        float f = Wb[i];
        int o, k;
        if (MODE == 0) { o = i >> 6; k = (i & 63) + 64; }   // Wb = W1r, k-high half
        else           { o = (i >> 7) + 64; k = i & 127; }  // Wb = W2r, o-high half
        int idx = (o * 128 + k) ^ ((o & 7) << 3);
        wlds[idx] = f2bf(f);
    }
    if (tid < 128) {
        float bv;
        if (MODE == 0) bv = bias[tid];
        else bv = (tid < 64) ? 0.f : bias[tid - 64];
        bs[tid] = bv;
    }
    __syncthreads();

    int lane = tid & 63, wid = tid >> 6;
    int l16 = lane & 15, lg = lane >> 4;
    long n0 = (long)blockIdx.x * 128 + wid * 32;
    const unsigned short* A0 = A + (n0 + l16) * 128;
    const unsigned short* A1 = A + (n0 + 16 + l16) * 128;

    f32x4 acc[2][8];
#pragma unroll
    for (int m = 0; m < 2; ++m)
#pragma unroll
        for (int ot = 0; ot < 8; ++ot)
            acc[m][ot] = (f32x4){0.f, 0.f, 0.f, 0.f};

#pragma unroll
    for (int ks = 0; ks < 4; ++ks) {
        int k0 = ks * 32;
        bf16x8 a0 = *(const bf16x8*)&A0[k0 + 8 * lg];
        bf16x8 a1 = *(const bf16x8*)&A1[k0 + 8 * lg];
#pragma unroll
        for (int ot = 0; ot < 8; ++ot) {
            int o = ot * 16 + l16;
            bf16x8 b = *(const bf16x8*)&wlds[(o * 128 + k0 + 8 * lg) ^ ((o & 7) << 3)];
            acc[0][ot] = __builtin_amdgcn_mfma_f32_16x16x32_bf16(a0, b, acc[0][ot], 0, 0, 0);
            acc[1][ot] = __builtin_amdgcn_mfma_f32_16x16x32_bf16(a1, b, acc[1][ot], 0, 0, 0);
        }
    }

    // epilogue: D row = (lane>>4)*4 + j (node), col = lane&15 (o)  [m89 layout]
    float bval[8];
#pragma unroll
    for (int ot = 0; ot < 8; ++ot) bval[ot] = bs[ot * 16 + l16];
#pragma unroll
    for (int m = 0; m < 2; ++m) {
        long nb = n0 + m * 16 + lg * 4;
#pragma unroll
        for (int j = 0; j < 4; ++j) {
            long n = nb + j;
            if (n >= N) continue;
#pragma unroll
            for (int ot = 0; ot < 8; ++ot) {
                float v = acc[m][ot][j] + bval[ot];
                if (relu) v = fmaxf(v, 0.f);
                C[n * 128 + ot * 16 + l16] = f2bf(v);
            }
        }
    }
}

__global__ void linkpred_kernel(const void* pairs, const int* flag,
                                const unsigned short* __restrict__ h2,
                                const float* __restrict__ Wlp,
                                const float* __restrict__ blp,
                                float* __restrict__ out, long P) {
    __shared__ float w[128];
    __shared__ float bb;
    int tid = threadIdx.x;
    if (tid < 128) w[tid] = Wlp[tid];
    if (tid == 0) bb = blp[0];
    __syncthreads();
    long p = (long)blockIdx.x * 256 + tid;
    if (p >= P) return;
    int is64 = *flag;
    long s = load_idx(pairs, 2 * p, is64);
    long d = load_idx(pairs, 2 * p + 1, is64);
    float acc = bb;
    const uint4* hs = (const uint4*)(h2 + s * 64);
    const uint4* hd = (const uint4*)(h2 + d * 64);
#pragma unroll
    for (int jq = 0; jq < 8; ++jq) {
        uint4 v = hs[jq];
        const float* wq = &w[jq * 8];
        acc += b2f((unsigned short)(v.x & 0xffff)) * wq[0] + b2f((unsigned short)(v.x >> 16)) * wq[1];
        acc += b2f((unsigned short)(v.y & 0xffff)) * wq[2] + b2f((unsigned short)(v.y >> 16)) * wq[3];
        acc += b2f((unsigned short)(v.z & 0xffff)) * wq[4] + b2f((unsigned short)(v.z >> 16)) * wq[5];
        acc += b2f((unsigned short)(v.w & 0xffff)) * wq[6] + b2f((unsigned short)(v.w >> 16)) * wq[7];
    }
#pragma unroll
    for (int jq = 0; jq < 8; ++jq) {
        uint4 v = hd[jq];
        const float* wq = &w[64 + jq * 8];
        acc += b2f((unsigned short)(v.x & 0xffff)) * wq[0] + b2f((unsigned short)(v.x >> 16)) * wq[1];
        acc += b2f((unsigned short)(v.y & 0xffff)) * wq[2] + b2f((unsigned short)(v.y >> 16)) * wq[3];
        acc += b2f((unsigned short)(v.z & 0xffff)) * wq[4] + b2f((unsigned short)(v.z >> 16)) * wq[5];
        acc += b2f((unsigned short)(v.w & 0xffff)) * wq[6] + b2f((unsigned short)(v.w >> 16)) * wq[7];
    }
    out[p] = 1.0f / (1.0f + expf(-acc));
}

extern "C" void kernel_launch(void* const* d_in, const int* in_sizes, int n_in,
                              void* d_out, int out_size, void* d_ws, size_t ws_size,
                              hipStream_t stream) {
    const float* x    = (const float*)d_in[0];
    const void*  eidx  = d_in[1];
    const void*  pairs = d_in[2];
    const float* W1l = (const float*)d_in[3];
    const float* W1r = (const float*)d_in[4];
    const float* b1  = (const float*)d_in[5];
    const float* W2l = (const float*)d_in[6];
    const float* W2r = (const float*)d_in[7];
    const float* b2  = (const float*)d_in[8];
    const float* Wlp = (const float*)d_in[9];
    const float* blp = (const float*)d_in[10];
    float* out = (float*)d_out;

    long N = in_sizes[0] / 64;
    long E = in_sizes[1] / 2;
    long P = in_sizes[2] / 2;
    long N_PAD = (N + 127) & ~127L;

    char* w = (char*)d_ws;
    auto alloc = [&](size_t bytes) {
        char* p = w;
        w += (bytes + 255) & ~(size_t)255;
        return p;
    };
    int* row_start = (int*)alloc((N + 1) * sizeof(int));
    int* cursor    = (int*)alloc(N * sizeof(int));
    int* csr_src   = (int*)alloc(E * sizeof(int));
    int* partial   = (int*)alloc(1024 * sizeof(int));
    int* flag      = (int*)alloc(64);
    unsigned short* xa = (unsigned short*)alloc((size_t)N_PAD * 128 * 2);
    unsigned short* h1 = (unsigned short*)alloc((size_t)N_PAD * 128 * 2);
    unsigned short* gr = (unsigned short*)alloc((size_t)N_PAD * 128 * 2);
    unsigned short* h2 = (unsigned short*)alloc((size_t)N * 64 * 2);

    hipMemsetAsync(cursor, 0, N * sizeof(int), stream);
    detect64_kernel<<<1, 1, 0, stream>>>(eidx, flag);

    unsigned eblocks = (unsigned)((E + 255) / 256);
    count_kernel<<<eblocks, 256, 0, stream>>>(eidx, flag, cursor, E);

    int NB = (int)((N + 1023) / 1024);
    scan_partial_kernel<<<NB, 256, 0, stream>>>(cursor, partial, N);
    scan_root_kernel<<<1, 1, 0, stream>>>(partial, row_start, NB, N);
    scan_apply_kernel<<<NB, 256, 0, stream>>>(cursor, partial, row_start, cursor, N);

    fill_kernel<<<eblocks, 256, 0, stream>>>(eidx, flag, row_start, cursor, csr_src, E);

    unsigned xcblocks = (unsigned)((N * 16 + 255) / 256);
    xcast_kernel<<<xcblocks, 256, 0, stream>>>(x, xa, N);

    unsigned nwaves_blocks = (unsigned)((N * 64 + 255) / 256);
    gather_xa_kernel<<<nwaves_blocks, 256, 0, stream>>>(row_start, csr_src, xa, N);

    unsigned gblocks = (unsigned)(N_PAD / 128);
    gemm_kernel<0><<<gblocks, 256, 0, stream>>>(xa, W1l, W1r, b1, h1, N, 1);
    gemm_kernel<1><<<gblocks, 256, 0, stream>>>(h1, W2l, W2r, b2, gr, N, 0);

    gather_h2_kernel<<<nwaves_blocks, 256, 0, stream>>>(row_start, csr_src, gr, h2, N);

    unsigned pblocks = (unsigned)((P + 255) / 256);
    linkpred_kernel<<<pblocks, 256, 0, stream>>>(pairs, flag, h2, Wlp, blp, out, P);
}

// Round 5
// 256.491 us; speedup vs baseline: 7.2090x; 1.4047x over previous
//
#include <hip/hip_runtime.h>

// GraphSAGE 2-layer + link predictor.
// CSR via 2-level bucket sort (all scatters LDS/L2-local):
//   bucket_count -> bucket_total -> bucket_base -> bucket_off -> bucket_scatter -> bucket_csr
// then: xcast -> gather_xa -> gemm<0> (h1) -> gemm<1> (gr) -> gather_h2 -> linkpred

typedef __attribute__((ext_vector_type(8))) short bf16x8;
typedef __attribute__((ext_vector_type(4))) float f32x4;

#define NBLK_A 256   // blocks in edge-chunk passes

__device__ __forceinline__ unsigned short f2bf(float f) {
    unsigned u = __float_as_uint(f);
    u = u + 0x7fffu + ((u >> 16) & 1u);   // RTNE
    return (unsigned short)(u >> 16);
}
__device__ __forceinline__ float b2f(unsigned short s) {
    return __uint_as_float(((unsigned)s) << 16);
}

__device__ __forceinline__ long load_idx(const void* p, long i, int is64) {
    if (is64) return (long)((const long long*)p)[i];
    return (long)((const int*)p)[i];
}

__global__ void detect64_kernel(const void* eidx, int* flag) {
    const unsigned* u = (const unsigned*)eidx;
    unsigned acc = 0;
    for (int i = 0; i < 128; ++i) acc |= u[2 * i + 1];
    *flag = (acc == 0u) ? 1 : 0;
}

// Pass A: per-block LDS histogram of dst>>8. blk_hist is bucket-major [NBK][NBLK_A].
__global__ void bucket_count_kernel(const void* eidx, const int* flag,
                                    int* __restrict__ blk_hist, long E, int NBK, int chunk) {
    __shared__ int h[512];          // NBK <= 512 (N <= 131072)
    int tid = threadIdx.x, b = blockIdx.x;
    for (int i = tid; i < NBK; i += 256) h[i] = 0;
    __syncthreads();
    int is64 = *flag;
    long e0 = (long)b * chunk;
    long e1 = e0 + chunk; if (e1 > E) e1 = E;
    for (long e = e0 + tid; e < e1; e += 256) {
        long dst = load_idx(eidx, E + e, is64);
        atomicAdd(&h[(int)(dst >> 8)], 1);
    }
    __syncthreads();
    for (int i = tid; i < NBK; i += 256) blk_hist[i * NBLK_A + b] = h[i];
}

// Pass B1: total[k] = sum_b blk_hist[k][b]
__global__ void bucket_total_kernel(const int* __restrict__ blk_hist, int* __restrict__ total) {
    __shared__ int ts[256];
    int k = blockIdx.x, t = threadIdx.x;
    ts[t] = blk_hist[k * NBLK_A + t];
    __syncthreads();
    for (int off = 128; off > 0; off >>= 1) {
        if (t < off) ts[t] += ts[t + off];
        __syncthreads();
    }
    if (t == 0) total[k] = ts[0];
}

// Pass B2: exclusive scan of bucket totals; also row_start[N] = E.
__global__ void bucket_base_kernel(const int* __restrict__ total, int* __restrict__ base,
                                   int* __restrict__ row_start, int NBK, long N, long E) {
    int acc = 0;
    for (int k = 0; k < NBK; ++k) { base[k] = acc; acc += total[k]; }
    base[NBK] = acc;
    row_start[N] = (int)E;
}

// Pass B3: blk_hist[k][b] <- base[k] + exclusive_scan_b(blk_hist[k][:])
__global__ void bucket_off_kernel(int* __restrict__ blk_hist, const int* __restrict__ base) {
    __shared__ int ts[256];
    int k = blockIdx.x, t = threadIdx.x;
    int v = blk_hist[k * NBLK_A + t];
    ts[t] = v; __syncthreads();
    for (int off = 1; off < 256; off <<= 1) {
        int u = (t >= off) ? ts[t - off] : 0;
        __syncthreads();
        ts[t] += u;
        __syncthreads();
    }
    blk_hist[k * NBLK_A + t] = base[k] + ts[t] - v;
}

// Pass C: scatter packed (dst_local<<24 | src) into bucket-contiguous regions.
// Positions come from LDS cursors -> writes are L2-local (~16-edge runs per (blk,bkt)).
__global__ void bucket_scatter_kernel(const void* eidx, const int* flag,
                                      const int* __restrict__ blk_hist,
                                      unsigned* __restrict__ ebuf, long E, int NBK, int chunk) {
    __shared__ int cur[512];
    int tid = threadIdx.x, b = blockIdx.x;
    for (int i = tid; i < NBK; i += 256) cur[i] = blk_hist[i * NBLK_A + b];
    __syncthreads();
    int is64 = *flag;
    long e0 = (long)b * chunk;
    long e1 = e0 + chunk; if (e1 > E) e1 = E;
    for (long e = e0 + tid; e < e1; e += 256) {
        long src = load_idx(eidx, e, is64);
        long dst = load_idx(eidx, E + e, is64);
        int pos = atomicAdd(&cur[(int)(dst >> 8)], 1);
        ebuf[pos] = (unsigned)src | ((unsigned)(dst & 255) << 24);  // src < 2^24
    }
}

// Pass D: per-bucket counting sort in LDS -> coalesced row_start + L2-local csr writes.
__global__ void bucket_csr_kernel(const unsigned* __restrict__ ebuf, const int* __restrict__ base,
                                  int* __restrict__ csr_src, int* __restrict__ row_start, long N) {
    __shared__ int cnt[256], sc[256], cur[256];
    int k = blockIdx.x, t = threadIdx.x;
    int bstart = base[k], bend = base[k + 1];
    cnt[t] = 0;
    __syncthreads();
    for (int i = bstart + t; i < bend; i += 256)
        atomicAdd(&cnt[ebuf[i] >> 24], 1);
    __syncthreads();
    int c = cnt[t];
    sc[t] = c; __syncthreads();
    for (int off = 1; off < 256; off <<= 1) {
        int u = (t >= off) ? sc[t - off] : 0;
        __syncthreads();
        sc[t] += u;
        __syncthreads();
    }
    int loff = sc[t] - c;
    cur[t] = loff;
    long n = (long)k * 256 + t;
    if (n < N) row_start[n] = bstart + loff;
    __syncthreads();
    for (int i = bstart + t; i < bend; i += 256) {
        unsigned v = ebuf[i];
        int dl = (int)(v >> 24);
        int p = atomicAdd(&cur[dl], 1);
        csr_src[bstart + p] = (int)(v & 0xFFFFFFu);
    }
}

// x (f32) -> xa[n][64+f] (bf16). One thread per 4 floats.
__global__ void xcast_kernel(const float* __restrict__ x, unsigned short* __restrict__ xa, long N) {
    long t = (long)blockIdx.x * 256 + threadIdx.x;
    long n = t >> 4;
    int q = (int)(t & 15);
    if (n >= N) return;
    float4 v = *(const float4*)&x[n * 64 + q * 4];
    uint2 u;
    u.x = (unsigned)f2bf(v.x) | ((unsigned)f2bf(v.y) << 16);
    u.y = (unsigned)f2bf(v.z) | ((unsigned)f2bf(v.w) << 16);
    *(uint2*)&xa[n * 128 + 64 + q * 4] = u;
}

// One wave per node; lane f: xa[n][f] = bf16( mean_nbr x_bf16[src][f] )
__global__ void gather_xa_kernel(const int* __restrict__ row_start, const int* __restrict__ csr,
                                 unsigned short* __restrict__ xa, long N) {
    long gid = (long)blockIdx.x * 256 + threadIdx.x;
    long n = gid >> 6;
    int f = (int)(gid & 63);
    if (n >= N) return;
    int s = row_start[n], e = row_start[n + 1];
    float a0 = 0.f, a1 = 0.f, a2 = 0.f, a3 = 0.f;
    int j = s;
    for (; j + 4 <= e; j += 4) {
        int i0 = csr[j], i1 = csr[j + 1], i2 = csr[j + 2], i3 = csr[j + 3];
        a0 += b2f(xa[(long)i0 * 128 + 64 + f]);
        a1 += b2f(xa[(long)i1 * 128 + 64 + f]);
        a2 += b2f(xa[(long)i2 * 128 + 64 + f]);
        a3 += b2f(xa[(long)i3 * 128 + 64 + f]);
    }
    for (; j < e; ++j) a0 += b2f(xa[(long)csr[j] * 128 + 64 + f]);
    float sum = (a0 + a1) + (a2 + a3);
    float deg = (float)(e - s);
    xa[n * 128 + f] = f2bf(sum / fmaxf(deg, 1.0f));
}

// h2[n][f] = bf16( mean_nbr gr[src][f] + gr[n][64+f] )
__global__ void gather_h2_kernel(const int* __restrict__ row_start, const int* __restrict__ csr,
                                 const unsigned short* __restrict__ gr,
                                 unsigned short* __restrict__ h2, long N) {
    long gid = (long)blockIdx.x * 256 + threadIdx.x;
    long n = gid >> 6;
    int f = (int)(gid & 63);
    if (n >= N) return;
    int s = row_start[n], e = row_start[n + 1];
    float a0 = 0.f, a1 = 0.f, a2 = 0.f, a3 = 0.f;
    int j = s;
    for (; j + 4 <= e; j += 4) {
        int i0 = csr[j], i1 = csr[j + 1], i2 = csr[j + 2], i3 = csr[j + 3];
        a0 += b2f(gr[(long)i0 * 128 + f]);
        a1 += b2f(gr[(long)i1 * 128 + f]);
        a2 += b2f(gr[(long)i2 * 128 + f]);
        a3 += b2f(gr[(long)i3 * 128 + f]);
    }
    for (; j < e; ++j) a0 += b2f(gr[(long)csr[j] * 128 + f]);
    float sum = (a0 + a1) + (a2 + a3);
    float deg = (float)(e - s);
    h2[n * 64 + f] = f2bf(sum / fmaxf(deg, 1.0f) + b2f(gr[n * 128 + 64 + f]));
}

// ---------------- MFMA GEMM: C = act(A @ W'.T + b') ----------------
// MODE 0 (layer1): W'[o][k] = k<64 ? Wa[o][k] : Wb[o][k-64]   (Wa,Wb are 128x64)
// MODE 1 (layer2): W'[o][k] = o<64 ? Wa[o][k] : Wb[o-64][k]   (Wa,Wb are 64x128)
template <int MODE>
__global__ void gemm_kernel(const unsigned short* __restrict__ A,
                            const float* __restrict__ Wa, const float* __restrict__ Wb,
                            const float* __restrict__ bias,
                            unsigned short* __restrict__ C, long N, int relu) {
    __shared__ unsigned short wlds[128 * 128];  // bf16, XOR-swizzled: idx ^= (o&7)<<3
    __shared__ float bs[128];
    int tid = threadIdx.x;

    for (int i = tid; i < 8192; i += 256) {
        float f = Wa[i];
        int o, k;
        if (MODE == 0) { o = i >> 6; k = i & 63; }
        else           { o = i >> 7; k = i & 127; }
        int idx = (o * 128 + k) ^ ((o & 7) << 3);
        wlds[idx] = f2bf(f);
    }
    for (int i = tid; i < 8192; i += 256) {
        float f = Wb[i];
        int o, k;
        if (MODE == 0) { o = i >> 6; k = (i & 63) + 64; }
        else           { o = (i >> 7) + 64; k = i & 127; }
        int idx = (o * 128 + k) ^ ((o & 7) << 3);
        wlds[idx] = f2bf(f);
    }
    if (tid < 128) {
        float bv;
        if (MODE == 0) bv = bias[tid];
        else bv = (tid < 64) ? 0.f : bias[tid - 64];
        bs[tid] = bv;
    }
    __syncthreads();

    int lane = tid & 63, wid = tid >> 6;
    int l16 = lane & 15, lg = lane >> 4;
    long n0 = (long)blockIdx.x * 128 + wid * 32;
    const unsigned short* A0 = A + (n0 + l16) * 128;
    const unsigned short* A1 = A + (n0 + 16 + l16) * 128;

    f32x4 acc[2][8];
#pragma unroll
    for (int m = 0; m < 2; ++m)
#pragma unroll
        for (int ot = 0; ot < 8; ++ot)
            acc[m][ot] = (f32x4){0.f, 0.f, 0.f, 0.f};

#pragma unroll
    for (int ks = 0; ks < 4; ++ks) {
        int k0 = ks * 32;
        bf16x8 a0 = *(const bf16x8*)&A0[k0 + 8 * lg];
        bf16x8 a1 = *(const bf16x8*)&A1[k0 + 8 * lg];
#pragma unroll
        for (int ot = 0; ot < 8; ++ot) {
            int o = ot * 16 + l16;
            bf16x8 b = *(const bf16x8*)&wlds[(o * 128 + k0 + 8 * lg) ^ ((o & 7) << 3)];
            acc[0][ot] = __builtin_amdgcn_mfma_f32_16x16x32_bf16(a0, b, acc[0][ot], 0, 0, 0);
            acc[1][ot] = __builtin_amdgcn_mfma_f32_16x16x32_bf16(a1, b, acc[1][ot], 0, 0, 0);
        }
    }

    float bval[8];
#pragma unroll
    for (int ot = 0; ot < 8; ++ot) bval[ot] = bs[ot * 16 + l16];
#pragma unroll
    for (int m = 0; m < 2; ++m) {
        long nb = n0 + m * 16 + lg * 4;
#pragma unroll
        for (int j = 0; j < 4; ++j) {
            long n = nb + j;
            if (n >= N) continue;
#pragma unroll
            for (int ot = 0; ot < 8; ++ot) {
                float v = acc[m][ot][j] + bval[ot];
                if (relu) v = fmaxf(v, 0.f);
                C[n * 128 + ot * 16 + l16] = f2bf(v);
            }
        }
    }
}

__global__ void linkpred_kernel(const void* pairs, const int* flag,
                                const unsigned short* __restrict__ h2,
                                const float* __restrict__ Wlp,
                                const float* __restrict__ blp,
                                float* __restrict__ out, long P) {
    __shared__ float w[128];
    __shared__ float bb;
    int tid = threadIdx.x;
    if (tid < 128) w[tid] = Wlp[tid];
    if (tid == 0) bb = blp[0];
    __syncthreads();
    long p = (long)blockIdx.x * 256 + tid;
    if (p >= P) return;
    int is64 = *flag;
    long s = load_idx(pairs, 2 * p, is64);
    long d = load_idx(pairs, 2 * p + 1, is64);
    float acc = bb;
    const uint4* hs = (const uint4*)(h2 + s * 64);
    const uint4* hd = (const uint4*)(h2 + d * 64);
#pragma unroll
    for (int jq = 0; jq < 8; ++jq) {
        uint4 v = hs[jq];
        const float* wq = &w[jq * 8];
        acc += b2f((unsigned short)(v.x & 0xffff)) * wq[0] + b2f((unsigned short)(v.x >> 16)) * wq[1];
        acc += b2f((unsigned short)(v.y & 0xffff)) * wq[2] + b2f((unsigned short)(v.y >> 16)) * wq[3];
        acc += b2f((unsigned short)(v.z & 0xffff)) * wq[4] + b2f((unsigned short)(v.z >> 16)) * wq[5];
        acc += b2f((unsigned short)(v.w & 0xffff)) * wq[6] + b2f((unsigned short)(v.w >> 16)) * wq[7];
    }
#pragma unroll
    for (int jq = 0; jq < 8; ++jq) {
        uint4 v = hd[jq];
        const float* wq = &w[64 + jq * 8];
        acc += b2f((unsigned short)(v.x & 0xffff)) * wq[0] + b2f((unsigned short)(v.x >> 16)) * wq[1];
        acc += b2f((unsigned short)(v.y & 0xffff)) * wq[2] + b2f((unsigned short)(v.y >> 16)) * wq[3];
        acc += b2f((unsigned short)(v.z & 0xffff)) * wq[4] + b2f((unsigned short)(v.z >> 16)) * wq[5];
        acc += b2f((unsigned short)(v.w & 0xffff)) * wq[6] + b2f((unsigned short)(v.w >> 16)) * wq[7];
    }
    out[p] = 1.0f / (1.0f + expf(-acc));
}

extern "C" void kernel_launch(void* const* d_in, const int* in_sizes, int n_in,
                              void* d_out, int out_size, void* d_ws, size_t ws_size,
                              hipStream_t stream) {
    const float* x    = (const float*)d_in[0];
    const void*  eidx  = d_in[1];
    const void*  pairs = d_in[2];
    const float* W1l = (const float*)d_in[3];
    const float* W1r = (const float*)d_in[4];
    const float* b1  = (const float*)d_in[5];
    const float* W2l = (const float*)d_in[6];
    const float* W2r = (const float*)d_in[7];
    const float* b2  = (const float*)d_in[8];
    const float* Wlp = (const float*)d_in[9];
    const float* blp = (const float*)d_in[10];
    float* out = (float*)d_out;

    long N = in_sizes[0] / 64;
    long E = in_sizes[1] / 2;
    long P = in_sizes[2] / 2;
    long N_PAD = (N + 127) & ~127L;
    int NBK = (int)((N + 255) >> 8);          // <= 512
    int chunk = (int)((E + NBLK_A - 1) / NBLK_A);

    char* w = (char*)d_ws;
    auto alloc = [&](size_t bytes) {
        char* p = w;
        w += (bytes + 255) & ~(size_t)255;
        return p;
    };
    int* row_start = (int*)alloc((N + 1) * sizeof(int));
    int* csr_src   = (int*)alloc(E * sizeof(int));
    int* blk_hist  = (int*)alloc((size_t)NBK * NBLK_A * sizeof(int));
    int* total     = (int*)alloc(NBK * sizeof(int));
    int* base      = (int*)alloc((NBK + 1) * sizeof(int));
    int* flag      = (int*)alloc(64);
    unsigned* ebuf = (unsigned*)alloc(E * sizeof(unsigned));
    unsigned short* xa = (unsigned short*)alloc((size_t)N_PAD * 128 * 2);
    unsigned short* h1 = (unsigned short*)alloc((size_t)N_PAD * 128 * 2);
    unsigned short* gr = (unsigned short*)alloc((size_t)N_PAD * 128 * 2);
    unsigned short* h2 = (unsigned short*)alloc((size_t)N * 64 * 2);

    detect64_kernel<<<1, 1, 0, stream>>>(eidx, flag);

    bucket_count_kernel<<<NBLK_A, 256, 0, stream>>>(eidx, flag, blk_hist, E, NBK, chunk);
    bucket_total_kernel<<<NBK, 256, 0, stream>>>(blk_hist, total);
    bucket_base_kernel<<<1, 1, 0, stream>>>(total, base, row_start, NBK, N, E);
    bucket_off_kernel<<<NBK, 256, 0, stream>>>(blk_hist, base);
    bucket_scatter_kernel<<<NBLK_A, 256, 0, stream>>>(eidx, flag, blk_hist, ebuf, E, NBK, chunk);
    bucket_csr_kernel<<<NBK, 256, 0, stream>>>(ebuf, base, csr_src, row_start, N);

    unsigned xcblocks = (unsigned)((N * 16 + 255) / 256);
    xcast_kernel<<<xcblocks, 256, 0, stream>>>(x, xa, N);

    unsigned nwaves_blocks = (unsigned)((N * 64 + 255) / 256);
    gather_xa_kernel<<<nwaves_blocks, 256, 0, stream>>>(row_start, csr_src, xa, N);

    unsigned gblocks = (unsigned)(N_PAD / 128);
    gemm_kernel<0><<<gblocks, 256, 0, stream>>>(xa, W1l, W1r, b1, h1, N, 1);
    gemm_kernel<1><<<gblocks, 256, 0, stream>>>(h1, W2l, W2r, b2, gr, N, 0);

    gather_h2_kernel<<<nwaves_blocks, 256, 0, stream>>>(row_start, csr_src, gr, h2, N);

    unsigned pblocks = (unsigned)((P + 255) / 256);
    linkpred_kernel<<<pblocks, 256, 0, stream>>>(pairs, flag, h2, Wlp, blp, out, P);
}

// Round 6
// 213.845 us; speedup vs baseline: 8.6466x; 1.1994x over previous
//
#include <hip/hip_runtime.h>

// GraphSAGE 2-layer + link predictor.
// CSR via 2-level bucket sort (all scatters LDS/L2-local):
//   bucket_count -> bucket_total -> bucket_base -> bucket_off -> bucket_scatter -> bucket_csr
// then: xcast -> gather<0> (xa) -> gemm<0> (h1) -> gemm<1> (gr) -> gather<1> (h2) -> linkpred
// Gathers: 4 neighbor rows per load instruction (lane l: row l>>4, feat quad l&15),
// 8 edges / iteration -> 8 lines in flight per wave; shfl_xor fold at the end.

typedef __attribute__((ext_vector_type(8))) short bf16x8;
typedef __attribute__((ext_vector_type(4))) float f32x4;

#define NBLK_A 256   // blocks in edge-chunk passes

__device__ __forceinline__ unsigned short f2bf(float f) {
    unsigned u = __float_as_uint(f);
    u = u + 0x7fffu + ((u >> 16) & 1u);   // RTNE
    return (unsigned short)(u >> 16);
}
__device__ __forceinline__ float b2f(unsigned short s) {
    return __uint_as_float(((unsigned)s) << 16);
}

__device__ __forceinline__ long load_idx(const void* p, long i, int is64) {
    if (is64) return (long)((const long long*)p)[i];
    return (long)((const int*)p)[i];
}

__global__ void detect64_kernel(const void* eidx, int* flag) {
    const unsigned* u = (const unsigned*)eidx;
    unsigned acc = 0;
    for (int i = 0; i < 128; ++i) acc |= u[2 * i + 1];
    *flag = (acc == 0u) ? 1 : 0;
}

// Pass A: per-block LDS histogram of dst>>8. blk_hist is bucket-major [NBK][NBLK_A].
__global__ void bucket_count_kernel(const void* eidx, const int* flag,
                                    int* __restrict__ blk_hist, long E, int NBK, int chunk) {
    __shared__ int h[512];          // NBK <= 512 (N <= 131072)
    int tid = threadIdx.x, b = blockIdx.x;
    for (int i = tid; i < NBK; i += 256) h[i] = 0;
    __syncthreads();
    int is64 = *flag;
    long e0 = (long)b * chunk;
    long e1 = e0 + chunk; if (e1 > E) e1 = E;
    for (long e = e0 + tid; e < e1; e += 256) {
        long dst = load_idx(eidx, E + e, is64);
        atomicAdd(&h[(int)(dst >> 8)], 1);
    }
    __syncthreads();
    for (int i = tid; i < NBK; i += 256) blk_hist[i * NBLK_A + b] = h[i];
}

// Pass B1: total[k] = sum_b blk_hist[k][b]
__global__ void bucket_total_kernel(const int* __restrict__ blk_hist, int* __restrict__ total) {
    __shared__ int ts[256];
    int k = blockIdx.x, t = threadIdx.x;
    ts[t] = blk_hist[k * NBLK_A + t];
    __syncthreads();
    for (int off = 128; off > 0; off >>= 1) {
        if (t < off) ts[t] += ts[t + off];
        __syncthreads();
    }
    if (t == 0) total[k] = ts[0];
}

// Pass B2: exclusive scan of bucket totals; also row_start[N] = E.
__global__ void bucket_base_kernel(const int* __restrict__ total, int* __restrict__ base,
                                   int* __restrict__ row_start, int NBK, long N, long E) {
    int acc = 0;
    for (int k = 0; k < NBK; ++k) { base[k] = acc; acc += total[k]; }
    base[NBK] = acc;
    row_start[N] = (int)E;
}

// Pass B3: blk_hist[k][b] <- base[k] + exclusive_scan_b(blk_hist[k][:])
__global__ void bucket_off_kernel(int* __restrict__ blk_hist, const int* __restrict__ base) {
    __shared__ int ts[256];
    int k = blockIdx.x, t = threadIdx.x;
    int v = blk_hist[k * NBLK_A + t];
    ts[t] = v; __syncthreads();
    for (int off = 1; off < 256; off <<= 1) {
        int u = (t >= off) ? ts[t - off] : 0;
        __syncthreads();
        ts[t] += u;
        __syncthreads();
    }
    blk_hist[k * NBLK_A + t] = base[k] + ts[t] - v;
}

// Pass C: scatter packed (dst_local<<24 | src) into bucket-contiguous regions.
__global__ void bucket_scatter_kernel(const void* eidx, const int* flag,
                                      const int* __restrict__ blk_hist,
                                      unsigned* __restrict__ ebuf, long E, int NBK, int chunk) {
    __shared__ int cur[512];
    int tid = threadIdx.x, b = blockIdx.x;
    for (int i = tid; i < NBK; i += 256) cur[i] = blk_hist[i * NBLK_A + b];
    __syncthreads();
    int is64 = *flag;
    long e0 = (long)b * chunk;
    long e1 = e0 + chunk; if (e1 > E) e1 = E;
    for (long e = e0 + tid; e < e1; e += 256) {
        long src = load_idx(eidx, e, is64);
        long dst = load_idx(eidx, E + e, is64);
        int pos = atomicAdd(&cur[(int)(dst >> 8)], 1);
        ebuf[pos] = (unsigned)src | ((unsigned)(dst & 255) << 24);  // src < 2^24
    }
}

// Pass D: per-bucket counting sort in LDS -> coalesced row_start + L2-local csr writes.
__global__ void bucket_csr_kernel(const unsigned* __restrict__ ebuf, const int* __restrict__ base,
                                  int* __restrict__ csr_src, int* __restrict__ row_start, long N) {
    __shared__ int cnt[256], sc[256], cur[256];
    int k = blockIdx.x, t = threadIdx.x;
    int bstart = base[k], bend = base[k + 1];
    cnt[t] = 0;
    __syncthreads();
    for (int i = bstart + t; i < bend; i += 256)
        atomicAdd(&cnt[ebuf[i] >> 24], 1);
    __syncthreads();
    int c = cnt[t];
    sc[t] = c; __syncthreads();
    for (int off = 1; off < 256; off <<= 1) {
        int u = (t >= off) ? sc[t - off] : 0;
        __syncthreads();
        sc[t] += u;
        __syncthreads();
    }
    int loff = sc[t] - c;
    cur[t] = loff;
    long n = (long)k * 256 + t;
    if (n < N) row_start[n] = bstart + loff;
    __syncthreads();
    for (int i = bstart + t; i < bend; i += 256) {
        unsigned v = ebuf[i];
        int dl = (int)(v >> 24);
        int p = atomicAdd(&cur[dl], 1);
        csr_src[bstart + p] = (int)(v & 0xFFFFFFu);
    }
}

// x (f32) -> xa[n][64+f] (bf16). One thread per 4 floats.
__global__ void xcast_kernel(const float* __restrict__ x, unsigned short* __restrict__ xa, long N) {
    long t = (long)blockIdx.x * 256 + threadIdx.x;
    long n = t >> 4;
    int q = (int)(t & 15);
    if (n >= N) return;
    float4 v = *(const float4*)&x[n * 64 + q * 4];
    uint2 u;
    u.x = (unsigned)f2bf(v.x) | ((unsigned)f2bf(v.y) << 16);
    u.y = (unsigned)f2bf(v.z) | ((unsigned)f2bf(v.w) << 16);
    *(uint2*)&xa[n * 128 + 64 + q * 4] = u;
}

// ---------------- high-MLP gather ----------------
// One wave per node. Lane l: row-group lg=l>>4 (4 rows/load-instr), feature quad fq=l&15.
// MODE 0: xa[n][0:64] = mean_nbr xa[src][64:128]
// MODE 1: h2[n][0:64] = mean_nbr gr[src][0:64] + gr[n][64:128]
template <int MODE>
__global__ void gather_kernel(const int* __restrict__ rs, const int* __restrict__ csr,
                              const unsigned short* __restrict__ T,
                              unsigned short* __restrict__ Out, long N) {
    long gid = (long)blockIdx.x * 256 + threadIdx.x;
    long n = gid >> 6;
    if (n >= N) return;
    int lane = (int)(gid & 63);
    int lg = lane >> 4;
    int fq = lane & 15;
    int s = rs[n], e = rs[n + 1];
    unsigned self0 = 0, self1 = 0;
    if (MODE == 1) {                       // issue self-row load early
        uint2 sv = *(const uint2*)&T[n * 128 + 64 + fq * 4];
        self0 = sv.x; self1 = sv.y;
    }
    const int OFF = (MODE == 0) ? 64 : 0;
    float a0 = 0.f, a1 = 0.f, a2 = 0.f, a3 = 0.f;
    for (int j = s; j < e; j += 8) {
        int j0 = j + lg, j1 = j + 4 + lg;
        int v0 = j0 < e, v1 = j1 < e;
        int s0 = csr[v0 ? j0 : s];
        int s1 = csr[v1 ? j1 : s];
        uint2 r0 = *(const uint2*)&T[(long)s0 * 128 + OFF + fq * 4];
        uint2 r1 = *(const uint2*)&T[(long)s1 * 128 + OFF + fq * 4];
        float m0 = v0 ? 1.f : 0.f, m1 = v1 ? 1.f : 0.f;
        a0 += m0 * b2f((unsigned short)(r0.x & 0xffff));
        a1 += m0 * b2f((unsigned short)(r0.x >> 16));
        a2 += m0 * b2f((unsigned short)(r0.y & 0xffff));
        a3 += m0 * b2f((unsigned short)(r0.y >> 16));
        a0 += m1 * b2f((unsigned short)(r1.x & 0xffff));
        a1 += m1 * b2f((unsigned short)(r1.x >> 16));
        a2 += m1 * b2f((unsigned short)(r1.y & 0xffff));
        a3 += m1 * b2f((unsigned short)(r1.y >> 16));
    }
    // fold the 4 row-groups
    a0 += __shfl_xor(a0, 16, 64);  a1 += __shfl_xor(a1, 16, 64);
    a2 += __shfl_xor(a2, 16, 64);  a3 += __shfl_xor(a3, 16, 64);
    a0 += __shfl_xor(a0, 32, 64);  a1 += __shfl_xor(a1, 32, 64);
    a2 += __shfl_xor(a2, 32, 64);  a3 += __shfl_xor(a3, 32, 64);
    if (lg == 0) {
        float inv = 1.0f / fmaxf((float)(e - s), 1.0f);
        a0 *= inv; a1 *= inv; a2 *= inv; a3 *= inv;
        if (MODE == 1) {
            a0 += b2f((unsigned short)(self0 & 0xffff));
            a1 += b2f((unsigned short)(self0 >> 16));
            a2 += b2f((unsigned short)(self1 & 0xffff));
            a3 += b2f((unsigned short)(self1 >> 16));
        }
        uint2 o;
        o.x = (unsigned)f2bf(a0) | ((unsigned)f2bf(a1) << 16);
        o.y = (unsigned)f2bf(a2) | ((unsigned)f2bf(a3) << 16);
        if (MODE == 0) *(uint2*)&Out[n * 128 + fq * 4] = o;
        else           *(uint2*)&Out[n * 64 + fq * 4] = o;
    }
}

// ---------------- MFMA GEMM: C = act(A @ W'.T + b') ----------------
// MODE 0 (layer1): W'[o][k] = k<64 ? Wa[o][k] : Wb[o][k-64]   (Wa,Wb are 128x64)
// MODE 1 (layer2): W'[o][k] = o<64 ? Wa[o][k] : Wb[o-64][k]   (Wa,Wb are 64x128)
template <int MODE>
__global__ void gemm_kernel(const unsigned short* __restrict__ A,
                            const float* __restrict__ Wa, const float* __restrict__ Wb,
                            const float* __restrict__ bias,
                            unsigned short* __restrict__ C, long N, int relu) {
    __shared__ unsigned short wlds[128 * 128];  // bf16, XOR-swizzled: idx ^= (o&7)<<3
    __shared__ float bs[128];
    int tid = threadIdx.x;

    for (int i = tid; i < 8192; i += 256) {
        float f = Wa[i];
        int o, k;
        if (MODE == 0) { o = i >> 6; k = i & 63; }
        else           { o = i >> 7; k = i & 127; }
        int idx = (o * 128 + k) ^ ((o & 7) << 3);
        wlds[idx] = f2bf(f);
    }
    for (int i = tid; i < 8192; i += 256) {
        float f = Wb[i];
        int o, k;
        if (MODE == 0) { o = i >> 6; k = (i & 63) + 64; }
        else           { o = (i >> 7) + 64; k = i & 127; }
        int idx = (o * 128 + k) ^ ((o & 7) << 3);
        wlds[idx] = f2bf(f);
    }
    if (tid < 128) {
        float bv;
        if (MODE == 0) bv = bias[tid];
        else bv = (tid < 64) ? 0.f : bias[tid - 64];
        bs[tid] = bv;
    }
    __syncthreads();

    int lane = tid & 63, wid = tid >> 6;
    int l16 = lane & 15, lg = lane >> 4;
    long n0 = (long)blockIdx.x * 128 + wid * 32;
    const unsigned short* A0 = A + (n0 + l16) * 128;
    const unsigned short* A1 = A + (n0 + 16 + l16) * 128;

    f32x4 acc[2][8];
#pragma unroll
    for (int m = 0; m < 2; ++m)
#pragma unroll
        for (int ot = 0; ot < 8; ++ot)
            acc[m][ot] = (f32x4){0.f, 0.f, 0.f, 0.f};

#pragma unroll
    for (int ks = 0; ks < 4; ++ks) {
        int k0 = ks * 32;
        bf16x8 a0 = *(const bf16x8*)&A0[k0 + 8 * lg];
        bf16x8 a1 = *(const bf16x8*)&A1[k0 + 8 * lg];
#pragma unroll
        for (int ot = 0; ot < 8; ++ot) {
            int o = ot * 16 + l16;
            bf16x8 b = *(const bf16x8*)&wlds[(o * 128 + k0 + 8 * lg) ^ ((o & 7) << 3)];
            acc[0][ot] = __builtin_amdgcn_mfma_f32_16x16x32_bf16(a0, b, acc[0][ot], 0, 0, 0);
            acc[1][ot] = __builtin_amdgcn_mfma_f32_16x16x32_bf16(a1, b, acc[1][ot], 0, 0, 0);
        }
    }

    float bval[8];
#pragma unroll
    for (int ot = 0; ot < 8; ++ot) bval[ot] = bs[ot * 16 + l16];
#pragma unroll
    for (int m = 0; m < 2; ++m) {
        long nb = n0 + m * 16 + lg * 4;
#pragma unroll
        for (int j = 0; j < 4; ++j) {
            long n = nb + j;
            if (n >= N) continue;
#pragma unroll
            for (int ot = 0; ot < 8; ++ot) {
                float v = acc[m][ot][j] + bval[ot];
                if (relu) v = fmaxf(v, 0.f);
                C[n * 128 + ot * 16 + l16] = f2bf(v);
            }
        }
    }
}

__global__ void linkpred_kernel(const void* pairs, const int* flag,
                                const unsigned short* __restrict__ h2,
                                const float* __restrict__ Wlp,
                                const float* __restrict__ blp,
                                float* __restrict__ out, long P) {
    __shared__ float w[128];
    __shared__ float bb;
    int tid = threadIdx.x;
    if (tid < 128) w[tid] = Wlp[tid];
    if (tid == 0) bb = blp[0];
    __syncthreads();
    long p = (long)blockIdx.x * 256 + tid;
    if (p >= P) return;
    int is64 = *flag;
    long s = load_idx(pairs, 2 * p, is64);
    long d = load_idx(pairs, 2 * p + 1, is64);
    float acc = bb;
    const uint4* hs = (const uint4*)(h2 + s * 64);
    const uint4* hd = (const uint4*)(h2 + d * 64);
#pragma unroll
    for (int jq = 0; jq < 8; ++jq) {
        uint4 v = hs[jq];
        const float* wq = &w[jq * 8];
        acc += b2f((unsigned short)(v.x & 0xffff)) * wq[0] + b2f((unsigned short)(v.x >> 16)) * wq[1];
        acc += b2f((unsigned short)(v.y & 0xffff)) * wq[2] + b2f((unsigned short)(v.y >> 16)) * wq[3];
        acc += b2f((unsigned short)(v.z & 0xffff)) * wq[4] + b2f((unsigned short)(v.z >> 16)) * wq[5];
        acc += b2f((unsigned short)(v.w & 0xffff)) * wq[6] + b2f((unsigned short)(v.w >> 16)) * wq[7];
    }
#pragma unroll
    for (int jq = 0; jq < 8; ++jq) {
        uint4 v = hd[jq];
        const float* wq = &w[64 + jq * 8];
        acc += b2f((unsigned short)(v.x & 0xffff)) * wq[0] + b2f((unsigned short)(v.x >> 16)) * wq[1];
        acc += b2f((unsigned short)(v.y & 0xffff)) * wq[2] + b2f((unsigned short)(v.y >> 16)) * wq[3];
        acc += b2f((unsigned short)(v.z & 0xffff)) * wq[4] + b2f((unsigned short)(v.z >> 16)) * wq[5];
        acc += b2f((unsigned short)(v.w & 0xffff)) * wq[6] + b2f((unsigned short)(v.w >> 16)) * wq[7];
    }
    out[p] = 1.0f / (1.0f + expf(-acc));
}

extern "C" void kernel_launch(void* const* d_in, const int* in_sizes, int n_in,
                              void* d_out, int out_size, void* d_ws, size_t ws_size,
                              hipStream_t stream) {
    const float* x    = (const float*)d_in[0];
    const void*  eidx  = d_in[1];
    const void*  pairs = d_in[2];
    const float* W1l = (const float*)d_in[3];
    const float* W1r = (const float*)d_in[4];
    const float* b1  = (const float*)d_in[5];
    const float* W2l = (const float*)d_in[6];
    const float* W2r = (const float*)d_in[7];
    const float* b2  = (const float*)d_in[8];
    const float* Wlp = (const float*)d_in[9];
    const float* blp = (const float*)d_in[10];
    float* out = (float*)d_out;

    long N = in_sizes[0] / 64;
    long E = in_sizes[1] / 2;
    long P = in_sizes[2] / 2;
    long N_PAD = (N + 127) & ~127L;
    int NBK = (int)((N + 255) >> 8);          // <= 512
    int chunk = (int)((E + NBLK_A - 1) / NBLK_A);

    char* w = (char*)d_ws;
    auto alloc = [&](size_t bytes) {
        char* p = w;
        w += (bytes + 255) & ~(size_t)255;
        return p;
    };
    int* row_start = (int*)alloc((N + 1) * sizeof(int));
    int* csr_src   = (int*)alloc(E * sizeof(int));
    int* blk_hist  = (int*)alloc((size_t)NBK * NBLK_A * sizeof(int));
    int* total     = (int*)alloc(NBK * sizeof(int));
    int* base      = (int*)alloc((NBK + 1) * sizeof(int));
    int* flag      = (int*)alloc(64);
    unsigned* ebuf = (unsigned*)alloc(E * sizeof(unsigned));
    unsigned short* xa = (unsigned short*)alloc((size_t)N_PAD * 128 * 2);
    unsigned short* h1 = (unsigned short*)alloc((size_t)N_PAD * 128 * 2);
    unsigned short* gr = (unsigned short*)alloc((size_t)N_PAD * 128 * 2);
    unsigned short* h2 = (unsigned short*)alloc((size_t)N * 64 * 2);

    detect64_kernel<<<1, 1, 0, stream>>>(eidx, flag);

    bucket_count_kernel<<<NBLK_A, 256, 0, stream>>>(eidx, flag, blk_hist, E, NBK, chunk);
    bucket_total_kernel<<<NBK, 256, 0, stream>>>(blk_hist, total);
    bucket_base_kernel<<<1, 1, 0, stream>>>(total, base, row_start, NBK, N, E);
    bucket_off_kernel<<<NBK, 256, 0, stream>>>(blk_hist, base);
    bucket_scatter_kernel<<<NBLK_A, 256, 0, stream>>>(eidx, flag, blk_hist, ebuf, E, NBK, chunk);
    bucket_csr_kernel<<<NBK, 256, 0, stream>>>(ebuf, base, csr_src, row_start, N);

    unsigned xcblocks = (unsigned)((N * 16 + 255) / 256);
    xcast_kernel<<<xcblocks, 256, 0, stream>>>(x, xa, N);

    unsigned nwaves_blocks = (unsigned)((N * 64 + 255) / 256);
    gather_kernel<0><<<nwaves_blocks, 256, 0, stream>>>(row_start, csr_src, xa, xa, N);

    unsigned gblocks = (unsigned)(N_PAD / 128);
    gemm_kernel<0><<<gblocks, 256, 0, stream>>>(xa, W1l, W1r, b1, h1, N, 1);
    gemm_kernel<1><<<gblocks, 256, 0, stream>>>(h1, W2l, W2r, b2, gr, N, 0);

    gather_kernel<1><<<nwaves_blocks, 256, 0, stream>>>(row_start, csr_src, gr, h2, N);

    unsigned pblocks = (unsigned)((P + 255) / 256);
    linkpred_kernel<<<pblocks, 256, 0, stream>>>(pairs, flag, h2, Wlp, blp, out, P);
}

// Round 7
// 204.904 us; speedup vs baseline: 9.0239x; 1.0436x over previous
//
#include <hip/hip_runtime.h>

// GraphSAGE 2-layer + link predictor.
// CSR via 2-level bucket sort -> xcast -> gather<0> (xa) -> fused_gemm (h1 in LDS, gr out)
// -> gather<1> (h2) -> linkpred.
// Gathers: 16 edges/iter, 16 lines in flight per wave, mask-free main loop.

typedef __attribute__((ext_vector_type(8))) short bf16x8;
typedef __attribute__((ext_vector_type(4))) float f32x4;

#define NBLK_A 256   // blocks in edge-chunk passes

__device__ __forceinline__ unsigned short f2bf(float f) {
    unsigned u = __float_as_uint(f);
    u = u + 0x7fffu + ((u >> 16) & 1u);   // RTNE
    return (unsigned short)(u >> 16);
}
__device__ __forceinline__ float b2f(unsigned short s) {
    return __uint_as_float(((unsigned)s) << 16);
}
__device__ __forceinline__ float uflo(unsigned v) { return __uint_as_float(v << 16); }
__device__ __forceinline__ float ufhi(unsigned v) { return __uint_as_float(v & 0xffff0000u); }

__device__ __forceinline__ long load_idx(const void* p, long i, int is64) {
    if (is64) return (long)((const long long*)p)[i];
    return (long)((const int*)p)[i];
}

__global__ void detect64_kernel(const void* eidx, int* flag) {
    const unsigned* u = (const unsigned*)eidx;
    unsigned acc = 0;
    for (int i = 0; i < 128; ++i) acc |= u[2 * i + 1];
    *flag = (acc == 0u) ? 1 : 0;
}

// Pass A: per-block LDS histogram of dst>>8. blk_hist is bucket-major [NBK][NBLK_A].
__global__ void bucket_count_kernel(const void* eidx, const int* flag,
                                    int* __restrict__ blk_hist, long E, int NBK, int chunk) {
    __shared__ int h[512];          // NBK <= 512 (N <= 131072)
    int tid = threadIdx.x, b = blockIdx.x;
    for (int i = tid; i < NBK; i += 256) h[i] = 0;
    __syncthreads();
    int is64 = *flag;
    long e0 = (long)b * chunk;
    long e1 = e0 + chunk; if (e1 > E) e1 = E;
    for (long e = e0 + tid; e < e1; e += 256) {
        long dst = load_idx(eidx, E + e, is64);
        atomicAdd(&h[(int)(dst >> 8)], 1);
    }
    __syncthreads();
    for (int i = tid; i < NBK; i += 256) blk_hist[i * NBLK_A + b] = h[i];
}

// Pass B1: total[k] = sum_b blk_hist[k][b]
__global__ void bucket_total_kernel(const int* __restrict__ blk_hist, int* __restrict__ total) {
    __shared__ int ts[256];
    int k = blockIdx.x, t = threadIdx.x;
    ts[t] = blk_hist[k * NBLK_A + t];
    __syncthreads();
    for (int off = 128; off > 0; off >>= 1) {
        if (t < off) ts[t] += ts[t + off];
        __syncthreads();
    }
    if (t == 0) total[k] = ts[0];
}

// Pass B2: exclusive scan of bucket totals; also row_start[N] = E.
__global__ void bucket_base_kernel(const int* __restrict__ total, int* __restrict__ base,
                                   int* __restrict__ row_start, int NBK, long N, long E) {
    int acc = 0;
    for (int k = 0; k < NBK; ++k) { base[k] = acc; acc += total[k]; }
    base[NBK] = acc;
    row_start[N] = (int)E;
}

// Pass B3: blk_hist[k][b] <- base[k] + exclusive_scan_b(blk_hist[k][:])
__global__ void bucket_off_kernel(int* __restrict__ blk_hist, const int* __restrict__ base) {
    __shared__ int ts[256];
    int k = blockIdx.x, t = threadIdx.x;
    int v = blk_hist[k * NBLK_A + t];
    ts[t] = v; __syncthreads();
    for (int off = 1; off < 256; off <<= 1) {
        int u = (t >= off) ? ts[t - off] : 0;
        __syncthreads();
        ts[t] += u;
        __syncthreads();
    }
    blk_hist[k * NBLK_A + t] = base[k] + ts[t] - v;
}

// Pass C: scatter packed (dst_local<<24 | src) into bucket-contiguous regions.
__global__ void bucket_scatter_kernel(const void* eidx, const int* flag,
                                      const int* __restrict__ blk_hist,
                                      unsigned* __restrict__ ebuf, long E, int NBK, int chunk) {
    __shared__ int cur[512];
    int tid = threadIdx.x, b = blockIdx.x;
    for (int i = tid; i < NBK; i += 256) cur[i] = blk_hist[i * NBLK_A + b];
    __syncthreads();
    int is64 = *flag;
    long e0 = (long)b * chunk;
    long e1 = e0 + chunk; if (e1 > E) e1 = E;
    for (long e = e0 + tid; e < e1; e += 256) {
        long src = load_idx(eidx, e, is64);
        long dst = load_idx(eidx, E + e, is64);
        int pos = atomicAdd(&cur[(int)(dst >> 8)], 1);
        ebuf[pos] = (unsigned)src | ((unsigned)(dst & 255) << 24);  // src < 2^24
    }
}

// Pass D: per-bucket counting sort in LDS -> coalesced row_start + L2-local csr writes.
__global__ void bucket_csr_kernel(const unsigned* __restrict__ ebuf, const int* __restrict__ base,
                                  int* __restrict__ csr_src, int* __restrict__ row_start, long N) {
    __shared__ int cnt[256], sc[256], cur[256];
    int k = blockIdx.x, t = threadIdx.x;
    int bstart = base[k], bend = base[k + 1];
    cnt[t] = 0;
    __syncthreads();
    for (int i = bstart + t; i < bend; i += 256)
        atomicAdd(&cnt[ebuf[i] >> 24], 1);
    __syncthreads();
    int c = cnt[t];
    sc[t] = c; __syncthreads();
    for (int off = 1; off < 256; off <<= 1) {
        int u = (t >= off) ? sc[t - off] : 0;
        __syncthreads();
        sc[t] += u;
        __syncthreads();
    }
    int loff = sc[t] - c;
    cur[t] = loff;
    long n = (long)k * 256 + t;
    if (n < N) row_start[n] = bstart + loff;
    __syncthreads();
    for (int i = bstart + t; i < bend; i += 256) {
        unsigned v = ebuf[i];
        int dl = (int)(v >> 24);
        int p = atomicAdd(&cur[dl], 1);
        csr_src[bstart + p] = (int)(v & 0xFFFFFFu);
    }
}

// x (f32) -> xa[n][64+f] (bf16). One thread per 4 floats.
__global__ void xcast_kernel(const float* __restrict__ x, unsigned short* __restrict__ xa, long N) {
    long t = (long)blockIdx.x * 256 + threadIdx.x;
    long n = t >> 4;
    int q = (int)(t & 15);
    if (n >= N) return;
    float4 v = *(const float4*)&x[n * 64 + q * 4];
    uint2 u;
    u.x = (unsigned)f2bf(v.x) | ((unsigned)f2bf(v.y) << 16);
    u.y = (unsigned)f2bf(v.z) | ((unsigned)f2bf(v.w) << 16);
    *(uint2*)&xa[n * 128 + 64 + q * 4] = u;
}

// ---------------- gather v3 ----------------
// One wave per node. Lane l: row-group lg=l>>4, feature quad fq=l&15.
// 16 edges/iter: 4 idx loads + 4 row loads -> 16 lines in flight. Mask-free main, masked tail.
// MODE 0: xa[n][0:64] = mean_nbr xa[src][64:128]
// MODE 1: h2[n][0:64] = mean_nbr gr[src][0:64] + gr[n][64:128]
template <int MODE>
__global__ void gather_kernel(const int* __restrict__ rs, const int* __restrict__ csr,
                              const unsigned short* __restrict__ T,
                              unsigned short* __restrict__ Out, long N) {
    long gid = (long)blockIdx.x * 256 + threadIdx.x;
    long n = gid >> 6;
    if (n >= N) return;
    int lane = (int)(gid & 63);
    int lg = lane >> 4;
    int fq = lane & 15;
    int s = rs[n], e = rs[n + 1];
    unsigned self0 = 0, self1 = 0;
    if (MODE == 1) {                       // issue self-row load early
        uint2 sv = *(const uint2*)&T[n * 128 + 64 + fq * 4];
        self0 = sv.x; self1 = sv.y;
    }
    const int OFF = (MODE == 0) ? 64 : 0;
    float a0 = 0.f, a1 = 0.f, a2 = 0.f, a3 = 0.f;
    int j = s;
    for (; j + 16 <= e; j += 16) {
        int i0 = csr[j + lg];
        int i1 = csr[j + 4 + lg];
        int i2 = csr[j + 8 + lg];
        int i3 = csr[j + 12 + lg];
        uint2 r0 = *(const uint2*)&T[(long)i0 * 128 + OFF + fq * 4];
        uint2 r1 = *(const uint2*)&T[(long)i1 * 128 + OFF + fq * 4];
        uint2 r2 = *(const uint2*)&T[(long)i2 * 128 + OFF + fq * 4];
        uint2 r3 = *(const uint2*)&T[(long)i3 * 128 + OFF + fq * 4];
        a0 += uflo(r0.x); a1 += ufhi(r0.x); a2 += uflo(r0.y); a3 += ufhi(r0.y);
        a0 += uflo(r1.x); a1 += ufhi(r1.x); a2 += uflo(r1.y); a3 += ufhi(r1.y);
        a0 += uflo(r2.x); a1 += ufhi(r2.x); a2 += uflo(r2.y); a3 += ufhi(r2.y);
        a0 += uflo(r3.x); a1 += ufhi(r3.x); a2 += uflo(r3.y); a3 += ufhi(r3.y);
    }
    if (j < e) {
#pragma unroll
        for (int t = 0; t < 4; ++t) {
            int pos = j + 4 * t + lg;
            int ok = pos < e;
            int si = csr[ok ? pos : s];          // address always in [s, e)
            uint2 r = *(const uint2*)&T[(long)si * 128 + OFF + fq * 4];
            float m = ok ? 1.f : 0.f;
            a0 += m * uflo(r.x); a1 += m * ufhi(r.x);
            a2 += m * uflo(r.y); a3 += m * ufhi(r.y);
        }
    }
    // fold the 4 row-groups
    a0 += __shfl_xor(a0, 16, 64);  a1 += __shfl_xor(a1, 16, 64);
    a2 += __shfl_xor(a2, 16, 64);  a3 += __shfl_xor(a3, 16, 64);
    a0 += __shfl_xor(a0, 32, 64);  a1 += __shfl_xor(a1, 32, 64);
    a2 += __shfl_xor(a2, 32, 64);  a3 += __shfl_xor(a3, 32, 64);
    if (lg == 0) {
        float inv = 1.0f / fmaxf((float)(e - s), 1.0f);
        a0 *= inv; a1 *= inv; a2 *= inv; a3 *= inv;
        if (MODE == 1) {
            a0 += b2f((unsigned short)(self0 & 0xffff));
            a1 += b2f((unsigned short)(self0 >> 16));
            a2 += b2f((unsigned short)(self1 & 0xffff));
            a3 += b2f((unsigned short)(self1 >> 16));
        }
        uint2 o;
        o.x = (unsigned)f2bf(a0) | ((unsigned)f2bf(a1) << 16);
        o.y = (unsigned)f2bf(a2) | ((unsigned)f2bf(a3) << 16);
        if (MODE == 0) *(uint2*)&Out[n * 128 + fq * 4] = o;
        else           *(uint2*)&Out[n * 64 + fq * 4] = o;
    }
}

// ---------------- fused MFMA GEMM: gr = layer2(relu(layer1(xa))) ----------------
// W1'[o][k] = k<64 ? W1l[o][k] : W1r[o][k-64]    (128x128)
// W2'[o][k] = o<64 ? W2l[o][k] : W2r[o-64][k]    (128x128)
// h1 lives only in a per-wave LDS region (XOR-swizzled); no inter-wave sharing.
// 512 threads = 8 waves x 32 nodes = 256 nodes/block. LDS = 32+32+64+1 KB.
__global__ __launch_bounds__(512) void fused_gemm_kernel(
        const unsigned short* __restrict__ A,
        const float* __restrict__ W1l, const float* __restrict__ W1r, const float* __restrict__ b1,
        const float* __restrict__ W2l, const float* __restrict__ W2r, const float* __restrict__ b2,
        unsigned short* __restrict__ gr, long N) {
    __shared__ unsigned short w1[128 * 128];
    __shared__ unsigned short w2[128 * 128];
    __shared__ unsigned short h1t[8][32 * 128];
    __shared__ float bs1[128], bs2[128];
    int tid = threadIdx.x;

    for (int i = tid; i < 8192; i += 512) {
        int o = i >> 6, k = i & 63;                       // W1l/W1r are 128x64
        w1[(o * 128 + k) ^ ((o & 7) << 3)] = f2bf(W1l[i]);
        w1[(o * 128 + k + 64) ^ ((o & 7) << 3)] = f2bf(W1r[i]);
        int o2 = i >> 7, k2 = i & 127;                    // W2l/W2r are 64x128
        w2[(o2 * 128 + k2) ^ ((o2 & 7) << 3)] = f2bf(W2l[i]);
        w2[((o2 + 64) * 128 + k2) ^ (((o2 + 64) & 7) << 3)] = f2bf(W2r[i]);
    }
    if (tid < 128) {
        bs1[tid] = b1[tid];
        bs2[tid] = (tid < 64) ? 0.f : b2[tid - 64];
    }
    __syncthreads();

    int lane = tid & 63, wid = tid >> 6;
    int l16 = lane & 15, lg = lane >> 4;
    long n0 = (long)blockIdx.x * 256 + wid * 32;
    const unsigned short* A0 = A + (n0 + l16) * 128;
    const unsigned short* A1 = A + (n0 + 16 + l16) * 128;
    unsigned short* hw = h1t[wid];

    f32x4 acc[2][8];
#pragma unroll
    for (int m = 0; m < 2; ++m)
#pragma unroll
        for (int ot = 0; ot < 8; ++ot)
            acc[m][ot] = (f32x4){0.f, 0.f, 0.f, 0.f};

    // ---- phase 1: h1 = relu(xa @ W1'.T + b1) ----
#pragma unroll
    for (int ks = 0; ks < 4; ++ks) {
        int k0 = ks * 32;
        bf16x8 a0 = *(const bf16x8*)&A0[k0 + 8 * lg];
        bf16x8 a1 = *(const bf16x8*)&A1[k0 + 8 * lg];
#pragma unroll
        for (int ot = 0; ot < 8; ++ot) {
            int o = ot * 16 + l16;
            bf16x8 b = *(const bf16x8*)&w1[(o * 128 + k0 + 8 * lg) ^ ((o & 7) << 3)];
            acc[0][ot] = __builtin_amdgcn_mfma_f32_16x16x32_bf16(a0, b, acc[0][ot], 0, 0, 0);
            acc[1][ot] = __builtin_amdgcn_mfma_f32_16x16x32_bf16(a1, b, acc[1][ot], 0, 0, 0);
        }
    }
    // epilogue 1 -> own-wave LDS region (row = node-local, col = o), swizzled
#pragma unroll
    for (int m = 0; m < 2; ++m) {
#pragma unroll
        for (int j = 0; j < 4; ++j) {
            int row = m * 16 + lg * 4 + j;
#pragma unroll
            for (int ot = 0; ot < 8; ++ot) {
                int col = ot * 16 + l16;
                float v = fmaxf(acc[m][ot][j] + bs1[col], 0.f);
                hw[(row * 128 + col) ^ ((row & 7) << 3)] = f2bf(v);
            }
        }
    }
    // ---- phase 2: gr = h1 @ W2'.T + b2' ----
#pragma unroll
    for (int m = 0; m < 2; ++m)
#pragma unroll
        for (int ot = 0; ot < 8; ++ot)
            acc[m][ot] = (f32x4){0.f, 0.f, 0.f, 0.f};
#pragma unroll
    for (int ks = 0; ks < 4; ++ks) {
        int k0 = ks * 32;
        bf16x8 a0 = *(const bf16x8*)&hw[(l16 * 128 + k0 + 8 * lg) ^ ((l16 & 7) << 3)];
        bf16x8 a1 = *(const bf16x8*)&hw[((16 + l16) * 128 + k0 + 8 * lg) ^ ((l16 & 7) << 3)];
#pragma unroll
        for (int ot = 0; ot < 8; ++ot) {
            int o = ot * 16 + l16;
            bf16x8 b = *(const bf16x8*)&w2[(o * 128 + k0 + 8 * lg) ^ ((o & 7) << 3)];
            acc[0][ot] = __builtin_amdgcn_mfma_f32_16x16x32_bf16(a0, b, acc[0][ot], 0, 0, 0);
            acc[1][ot] = __builtin_amdgcn_mfma_f32_16x16x32_bf16(a1, b, acc[1][ot], 0, 0, 0);
        }
    }
    float bval[8];
#pragma unroll
    for (int ot = 0; ot < 8; ++ot) bval[ot] = bs2[ot * 16 + l16];
#pragma unroll
    for (int m = 0; m < 2; ++m) {
        long nb = n0 + m * 16 + lg * 4;
#pragma unroll
        for (int j = 0; j < 4; ++j) {
            long n = nb + j;
            if (n >= N) continue;
#pragma unroll
            for (int ot = 0; ot < 8; ++ot)
                gr[n * 128 + ot * 16 + l16] = f2bf(acc[m][ot][j] + bval[ot]);
        }
    }
}

// linkpred v2: 32 lanes per pair (16 per endpoint row), shfl reduce.
__global__ void linkpred_kernel(const void* pairs, const int* flag,
                                const unsigned short* __restrict__ h2,
                                const float* __restrict__ Wlp,
                                const float* __restrict__ blp,
                                float* __restrict__ out, long P) {
    long gid = (long)blockIdx.x * 256 + threadIdx.x;
    long p = gid >> 5;
    if (p >= P) return;
    int l32 = (int)(gid & 31);
    int half = l32 >> 4;     // 0: src emb, 1: dst emb
    int fq = l32 & 15;
    int is64 = *flag;
    long node = load_idx(pairs, 2 * p + half, is64);
    uint2 r = *(const uint2*)&h2[node * 64 + fq * 4];
    float4 wv = *(const float4*)&Wlp[half * 64 + fq * 4];
    float acc = uflo(r.x) * wv.x + ufhi(r.x) * wv.y + uflo(r.y) * wv.z + ufhi(r.y) * wv.w;
    acc += __shfl_xor(acc, 1, 64);
    acc += __shfl_xor(acc, 2, 64);
    acc += __shfl_xor(acc, 4, 64);
    acc += __shfl_xor(acc, 8, 64);
    acc += __shfl_xor(acc, 16, 64);
    if (l32 == 0) out[p] = 1.0f / (1.0f + expf(-(acc + blp[0])));
}

extern "C" void kernel_launch(void* const* d_in, const int* in_sizes, int n_in,
                              void* d_out, int out_size, void* d_ws, size_t ws_size,
                              hipStream_t stream) {
    const float* x    = (const float*)d_in[0];
    const void*  eidx  = d_in[1];
    const void*  pairs = d_in[2];
    const float* W1l = (const float*)d_in[3];
    const float* W1r = (const float*)d_in[4];
    const float* b1  = (const float*)d_in[5];
    const float* W2l = (const float*)d_in[6];
    const float* W2r = (const float*)d_in[7];
    const float* b2  = (const float*)d_in[8];
    const float* Wlp = (const float*)d_in[9];
    const float* blp = (const float*)d_in[10];
    float* out = (float*)d_out;

    long N = in_sizes[0] / 64;
    long E = in_sizes[1] / 2;
    long P = in_sizes[2] / 2;
    long N_PAD = (N + 255) & ~255L;
    int NBK = (int)((N + 255) >> 8);          // <= 512
    int chunk = (int)((E + NBLK_A - 1) / NBLK_A);

    char* w = (char*)d_ws;
    auto alloc = [&](size_t bytes) {
        char* p = w;
        w += (bytes + 255) & ~(size_t)255;
        return p;
    };
    int* row_start = (int*)alloc((N + 1) * sizeof(int));
    int* csr_src   = (int*)alloc(E * sizeof(int));
    int* blk_hist  = (int*)alloc((size_t)NBK * NBLK_A * sizeof(int));
    int* total     = (int*)alloc(NBK * sizeof(int));
    int* base      = (int*)alloc((NBK + 1) * sizeof(int));
    int* flag      = (int*)alloc(64);
    unsigned* ebuf = (unsigned*)alloc(E * sizeof(unsigned));
    unsigned short* xa = (unsigned short*)alloc((size_t)N_PAD * 128 * 2);
    unsigned short* gr = (unsigned short*)alloc((size_t)N_PAD * 128 * 2);
    unsigned short* h2 = (unsigned short*)alloc((size_t)N * 64 * 2);

    detect64_kernel<<<1, 1, 0, stream>>>(eidx, flag);

    bucket_count_kernel<<<NBLK_A, 256, 0, stream>>>(eidx, flag, blk_hist, E, NBK, chunk);
    bucket_total_kernel<<<NBK, 256, 0, stream>>>(blk_hist, total);
    bucket_base_kernel<<<1, 1, 0, stream>>>(total, base, row_start, NBK, N, E);
    bucket_off_kernel<<<NBK, 256, 0, stream>>>(blk_hist, base);
    bucket_scatter_kernel<<<NBLK_A, 256, 0, stream>>>(eidx, flag, blk_hist, ebuf, E, NBK, chunk);
    bucket_csr_kernel<<<NBK, 256, 0, stream>>>(ebuf, base, csr_src, row_start, N);

    unsigned xcblocks = (unsigned)((N * 16 + 255) / 256);
    xcast_kernel<<<xcblocks, 256, 0, stream>>>(x, xa, N);

    unsigned nwaves_blocks = (unsigned)((N * 64 + 255) / 256);
    gather_kernel<0><<<nwaves_blocks, 256, 0, stream>>>(row_start, csr_src, xa, xa, N);

    unsigned gblocks = (unsigned)(N_PAD / 256);
    fused_gemm_kernel<<<gblocks, 512, 0, stream>>>(xa, W1l, W1r, b1, W2l, W2r, b2, gr, N);

    gather_kernel<1><<<nwaves_blocks, 256, 0, stream>>>(row_start, csr_src, gr, h2, N);

    unsigned pblocks = (unsigned)((P * 32 + 255) / 256);
    linkpred_kernel<<<pblocks, 256, 0, stream>>>(pairs, flag, h2, Wlp, blp, out, P);
}